// Round 16
// baseline (304.711 us; speedup 1.0000x reference)
//
#include <hip/hip_runtime.h>
#include <hip/hip_bf16.h>

// Sizes for this problem
#define T_SEQ 4096
#define C_DIM 1024
#define NH    16
#define HD    64
#define C3    3072

typedef __attribute__((ext_vector_type(8))) short short8;
typedef __attribute__((ext_vector_type(4))) short short4v;
typedef __attribute__((ext_vector_type(4))) float f32x4;
typedef __attribute__((ext_vector_type(16))) float f32x16;

__device__ __forceinline__ short f2bf(float f) {
  union { float f; unsigned u; } v; v.f = f;
  unsigned r = v.u + 0x7FFFu + ((v.u >> 16) & 1u);   // round-to-nearest-even
  return (short)(r >> 16);
}

__device__ __forceinline__ unsigned cvt_pk_bf16(float lo, float hi) {
  unsigned r;
  asm volatile("v_cvt_pk_bf16_f32 %0, %1, %2" : "=v"(r) : "v"(lo), "v"(hi));
  return r;
}

// single-instruction 2^x (exp2f w/o fast-math is a multi-inst ocml call)
__device__ __forceinline__ float exp2_fast(float x) {
  return __builtin_amdgcn_exp2f(x);
}

// cross-half (lane^32) max via ds_bpermute-based shfl (proven correct here;
// permlane32_swap-based reduce failed twice — suspected wait-state hazard).
__device__ __forceinline__ float max_half64(float v) {
  return fmaxf(v, __shfl_xor(v, 32, 64));
}

__device__ __forceinline__ float m3(float a, float b, float c) {
  return fmaxf(fmaxf(a, b), c);   // clang fuses to v_max3_f32
}

__device__ __forceinline__ void gld_lds16(const void* g, void* l) {
  __builtin_amdgcn_global_load_lds(
      (const __attribute__((address_space(1))) unsigned int*)g,
      (__attribute__((address_space(3))) unsigned int*)l, 16, 0, 0);
}

// ---------------- fp32 -> bf16 convert (x) ----------------
__global__ __launch_bounds__(256) void conv_bf16_kernel(const float* __restrict__ in,
                                                        short* __restrict__ out) {
  const size_t i = ((size_t)blockIdx.x * 256 + threadIdx.x) * 8;
  float4 v0 = *(const float4*)(in + i);
  float4 v1 = *(const float4*)(in + i + 4);
  short8 o;
  o[0] = f2bf(v0.x); o[1] = f2bf(v0.y); o[2] = f2bf(v0.z); o[3] = f2bf(v0.w);
  o[4] = f2bf(v1.x); o[5] = f2bf(v1.y); o[6] = f2bf(v1.z); o[7] = f2bf(v1.w);
  *(short8*)(out + i) = o;
}

// ---------------- both weights: fp32 [K][N] -> bf16 [N][K] transpose-convert ----------------
__global__ void trans_conv2_kernel(const float* __restrict__ wq, short* __restrict__ wqT,
                                   const float* __restrict__ wo, short* __restrict__ woT) {
  const float* in;
  short* out;
  int N, bx = blockIdx.x;
  if (bx < C3 / 32) { in = wq; out = wqT; N = C3; }
  else              { in = wo; out = woT; N = C_DIM; bx -= C3 / 32; }
  const int K = C_DIM;
  __shared__ float t[32][33];
  const int n0 = bx * 32, k0 = blockIdx.y * 32;
  const int tx = threadIdx.x, ty = threadIdx.y;
  for (int i = ty; i < 32; i += 8) t[i][tx] = in[(size_t)(k0 + i) * N + n0 + tx];
  __syncthreads();
  for (int i = ty; i < 32; i += 8) out[(size_t)(n0 + i) * K + k0 + tx] = f2bf(t[tx][i]);
}

// ---------------- bf16 GEMM: C[M,N] = A[M,K] * BT[N,K]^T (128x128 tile) ----------------
// Blocks with bn >= vcol0 write their tile TRANSPOSED into vTout[(col-vcol0)*M + row]
__global__ __launch_bounds__(256) void gemm_bt_kernel(const short* __restrict__ A,
                                                      const short* __restrict__ BT,
                                                      short* __restrict__ C,
                                                      short* __restrict__ vTout,
                                                      int vcol0,
                                                      int M, int N, int K) {
  __shared__ __align__(16) short As[128 * 32];
  __shared__ __align__(16) short Bs[128 * 32];
  const int tid = threadIdx.x;
  const int wid = tid >> 6;
  const int lane = tid & 63;
  const int l15 = lane & 15;
  const int l4 = lane >> 4;
  const int wr = wid >> 1;
  const int wc = wid & 1;

  // XCD-aware bijective swizzle (grid count divisible by 8)
  const int nwg = gridDim.x * gridDim.y;
  int lin = blockIdx.y * gridDim.x + blockIdx.x;
  lin = (lin & 7) * (nwg >> 3) + (lin >> 3);
  const int bm = (lin / gridDim.x) * 128;
  const int bn = (lin % gridDim.x) * 128;

  f32x4 acc[4][4];
#pragma unroll
  for (int m = 0; m < 4; ++m)
#pragma unroll
    for (int n = 0; n < 4; ++n) acc[m][n] = (f32x4){0.f, 0.f, 0.f, 0.f};

  const int ebase = wid * 1024;              // 1024 bf16 elements per wave (2 x 512)
  const int e0 = ebase + lane * 8;
  const int r0 = e0 >> 5, c0 = e0 & 31;
  const int r1 = r0 + 16;                    // e0 + 512

  for (int k0 = 0; k0 < K; k0 += 32) {
    __syncthreads();
    gld_lds16(A + (size_t)(bm + r0) * K + k0 + c0, As + ebase);
    gld_lds16(A + (size_t)(bm + r1) * K + k0 + c0, As + ebase + 512);
    gld_lds16(BT + (size_t)(bn + r0) * K + k0 + c0, Bs + ebase);
    gld_lds16(BT + (size_t)(bn + r1) * K + k0 + c0, Bs + ebase + 512);
    __syncthreads();

    short8 a[4], b[4];
#pragma unroll
    for (int m = 0; m < 4; ++m)
      a[m] = *(const short8*)&As[(wr * 64 + m * 16 + l15) * 32 + l4 * 8];
#pragma unroll
    for (int n = 0; n < 4; ++n)
      b[n] = *(const short8*)&Bs[(wc * 64 + n * 16 + l15) * 32 + l4 * 8];
#pragma unroll
    for (int m = 0; m < 4; ++m)
#pragma unroll
      for (int n = 0; n < 4; ++n)
        acc[m][n] = __builtin_amdgcn_mfma_f32_16x16x32_bf16(a[m], b[n], acc[m][n], 0, 0, 0);
  }

  if (bn >= vcol0) {
#pragma unroll
    for (int m = 0; m < 4; ++m) {
      const int row0 = bm + wr * 64 + m * 16 + l4 * 4;
#pragma unroll
      for (int n = 0; n < 4; ++n) {
        const int col = bn + wc * 64 + n * 16 + l15;
        short4v o;
#pragma unroll
        for (int r = 0; r < 4; ++r) o[r] = f2bf(acc[m][n][r]);
        *(short4v*)&vTout[(size_t)(col - vcol0) * M + row0] = o;
      }
    }
  } else {
#pragma unroll
    for (int m = 0; m < 4; ++m) {
      const int row0 = bm + wr * 64 + m * 16 + l4 * 4;
#pragma unroll
      for (int n = 0; n < 4; ++n) {
        const int col = bn + wc * 64 + n * 16 + l15;
#pragma unroll
        for (int r = 0; r < 4; ++r)
          C[(size_t)(row0 + r) * N + col] = f2bf(acc[m][n][r]);
      }
    }
  }
}

// ---------------- bf16 GEMM: 128x64 tile, fp32 out (GEMM2: 2 blocks/CU) ----------------
__global__ __launch_bounds__(256) void gemm_bt64_kernel(const short* __restrict__ A,
                                                        const short* __restrict__ BT,
                                                        float* __restrict__ C,
                                                        int M, int N, int K) {
  __shared__ __align__(16) short As[128 * 32];
  __shared__ __align__(16) short Bs[64 * 32];
  const int tid = threadIdx.x;
  const int wid = tid >> 6;
  const int lane = tid & 63;
  const int l15 = lane & 15;
  const int l4 = lane >> 4;
  const int wr = wid >> 1;
  const int wc = wid & 1;

  const int nwg = gridDim.x * gridDim.y;
  int lin = blockIdx.y * gridDim.x + blockIdx.x;
  lin = (lin & 7) * (nwg >> 3) + (lin >> 3);
  const int bm = (lin / gridDim.x) * 128;
  const int bn = (lin % gridDim.x) * 64;

  f32x4 acc[4][2];
#pragma unroll
  for (int m = 0; m < 4; ++m)
#pragma unroll
    for (int n = 0; n < 2; ++n) acc[m][n] = (f32x4){0.f, 0.f, 0.f, 0.f};

  const int ebase = wid * 1024;
  const int e0 = ebase + lane * 8;
  const int r0 = e0 >> 5, c0 = e0 & 31;
  const int r1 = r0 + 16;
  const int eb = wid * 512 + lane * 8;
  const int rb = eb >> 5, cb = eb & 31;

  for (int k0 = 0; k0 < K; k0 += 32) {
    __syncthreads();
    gld_lds16(A + (size_t)(bm + r0) * K + k0 + c0, As + ebase);
    gld_lds16(A + (size_t)(bm + r1) * K + k0 + c0, As + ebase + 512);
    gld_lds16(BT + (size_t)(bn + rb) * K + k0 + cb, Bs + eb);
    __syncthreads();

    short8 a[4], b[2];
#pragma unroll
    for (int m = 0; m < 4; ++m)
      a[m] = *(const short8*)&As[(wr * 64 + m * 16 + l15) * 32 + l4 * 8];
#pragma unroll
    for (int n = 0; n < 2; ++n)
      b[n] = *(const short8*)&Bs[(wc * 32 + n * 16 + l15) * 32 + l4 * 8];
#pragma unroll
    for (int m = 0; m < 4; ++m)
#pragma unroll
      for (int n = 0; n < 2; ++n)
        acc[m][n] = __builtin_amdgcn_mfma_f32_16x16x32_bf16(a[m], b[n], acc[m][n], 0, 0, 0);
  }

#pragma unroll
  for (int m = 0; m < 4; ++m) {
    const int row0 = bm + wr * 64 + m * 16 + l4 * 4;
#pragma unroll
    for (int n = 0; n < 2; ++n) {
      const int col = bn + wc * 32 + n * 16 + l15;
#pragma unroll
      for (int r = 0; r < 4; ++r)
        C[(size_t)(row0 + r) * N + col] = acc[m][n][r];
    }
  }
}

// ---------------- flash attention: 4-way KV split (chain 1024), 64 q per wave ----------------
// 512 blocks x 512 threads = 8 waves: group g = w>>1 covers KV quarter g; wg = w&1
// selects 64 q rows. Loop body identical to the proven 2-way version; NT = 32.
// End: 2-round tree merge of the 4 partials via LDS (exact online-softmax combine).
__global__ __launch_bounds__(512, 4) void attn_kernel(const short* __restrict__ qkv,
                                                      const short* __restrict__ vT,
                                                      short* __restrict__ y) {
  // XCD-aware: heads {2x, 2x+1} -> XCD x (round-robin bid%8 assumption)
  const int bid = blockIdx.x;
  const int xcd = bid & 7, slot = bid >> 3;      // slot 0..63
  const int h = xcd * 2 + (slot >> 5);
  const int q0 = (slot & 31) * 128;

  const int tid = threadIdx.x;
  const int w = tid >> 6, lane = tid & 63, l31 = lane & 31, l1 = lane >> 5;
  const int g = w >> 1, wg = w & 1;              // group = KV quarter; wg = q-wave
  const int kvbase = g * (T_SEQ / 4);

  // 68 KB shared: [0,16384) shorts = K staging (4 grp x 2 buf x 2048),
  // [16384,32768) = V staging; merge Oex/mex (4 slots x 16KB + ml) overlays after.
  __shared__ __align__(16) short SM[34816];

  // Q B-fragments: subtile A = q0+wg*64+l31, B = +32; k = d = ks*16 + l1*8 + j
  short8 qfA[4], qfB[4];
  {
    const short* qp = qkv + (size_t)(q0 + wg * 64 + l31) * C3 + h * 64 + l1 * 8;
#pragma unroll
    for (int ks = 0; ks < 4; ++ks) {
      qfA[ks] = *(const short8*)(qp + ks * 16);
      qfB[ks] = *(const short8*)(qp + (size_t)32 * C3 + ks * 16);
    }
  }

  f32x16 oaA0, oaA1, oaB0, oaB1;   // O^T: col q=l31, row d=(r&3)+8*(r>>2)+4*l1 (+32 for *1)
#pragma unroll
  for (int r = 0; r < 16; ++r) { oaA0[r] = 0.f; oaA1[r] = 0.f; oaB0[r] = 0.f; oaB1[r] = 0.f; }
  float mA = -INFINITY, lA = 0.f, mB = -INFINITY, lB = 0.f;
  const float SCL = 0.125f * 1.44269504f;          // 1/sqrt(64) * log2(e)
  const float TH = 8.0f / SCL;                     // defer-max threshold (p <= 2^8)

  // staging pointers (wave-load i covers 8 rows; rows = wg*16 + i*8 + (lane>>3))
  const int csw = ((lane & 7) << 3) ^ ((lane >> 3) << 3);
  const short* kpt = qkv + 1024 + h * 64 + csw +
                     (size_t)(kvbase + wg * 16 + (lane >> 3)) * C3;
  const int lu = (lane & 7) ^ (lane >> 3);
  const short* vpt = vT + (size_t)(h * 64 + wg * 16 + (lane >> 3) + (lu >> 2) * 32) * T_SEQ +
                     kvbase + (lu & 3) * 8;
  const int rswz = (l31 & 7) << 3;

  short* const Kbase = SM + g * 4096;
  short* const Vbase = SM + 16384 + g * 4096;

  auto stage = [&](int buf) {
#pragma unroll
    for (int i = 0; i < 2; ++i) {
      gld_lds16(kpt + (size_t)i * 8 * C3, Kbase + buf * 2048 + wg * 1024 + i * 512);
      gld_lds16(vpt + (size_t)i * 8 * T_SEQ, Vbase + buf * 2048 + wg * 1024 + i * 512);
    }
  };

  stage(0);
  kpt += (size_t)32 * C3;
  vpt += 32;

  const int NT = (T_SEQ / 4) / 32;   // 32 tiles per quarter
  for (int t = 0; t < NT; ++t) {
    const int cur = t & 1;
    __builtin_amdgcn_s_barrier();            // done reading buf cur^1
    if (t + 1 < NT) {
      stage(cur ^ 1);
      kpt += (size_t)32 * C3;
      vpt += 32;
      asm volatile("s_waitcnt vmcnt(4)" ::: "memory");   // tile-t loads landed; t+1's fly
    } else {
      asm volatile("s_waitcnt vmcnt(0)" ::: "memory");
    }
    __builtin_amdgcn_s_barrier();            // tile-t data visible

    const short* Kb = Kbase + cur * 2048;
    const short* Vb = Vbase + cur * 2048;

    // S^T = K Q^T for both q-subtiles (K frags shared)
    f32x16 sA, sB;
#pragma unroll
    for (int r = 0; r < 16; ++r) { sA[r] = 0.f; sB[r] = 0.f; }
    __builtin_amdgcn_s_setprio(1);
#pragma unroll
    for (int ks = 0; ks < 4; ++ks) {
      const int c = (ks * 16 + l1 * 8) ^ rswz;
      short8 kf = *(const short8*)&Kb[l31 * 64 + c];
      sA = __builtin_amdgcn_mfma_f32_32x32x16_bf16(kf, qfA[ks], sA, 0, 0, 0);
      sB = __builtin_amdgcn_mfma_f32_32x32x16_bf16(kf, qfB[ks], sB, 0, 0, 0);
    }
    __builtin_amdgcn_s_setprio(0);

    // lane-local maxes via max3 trees
    float tmA, tmB;
    {
      float v0 = m3(sA[0], sA[1], sA[2]);
      float v1 = m3(sA[3], sA[4], sA[5]);
      float v2 = m3(sA[6], sA[7], sA[8]);
      float v3 = m3(sA[9], sA[10], sA[11]);
      float v4 = m3(sA[12], sA[13], sA[14]);
      tmA = fmaxf(m3(v0, v1, v2), m3(v3, v4, sA[15]));
      float u0 = m3(sB[0], sB[1], sB[2]);
      float u1 = m3(sB[3], sB[4], sB[5]);
      float u2 = m3(sB[6], sB[7], sB[8]);
      float u3 = m3(sB[9], sB[10], sB[11]);
      float u4 = m3(sB[12], sB[13], sB[14]);
      tmB = fmaxf(m3(u0, u1, u2), m3(u3, u4, sB[15]));
    }

    // defer-max: single 64-lane ballot for both subtiles keeps halves consistent
    if (__any(fmaxf(tmA - mA, tmB - mB) > TH)) {
      const float txA = max_half64(tmA);
      const float mnA = fmaxf(mA, txA);
      const float alA = exp2_fast((mA - mnA) * SCL);
      mA = mnA; lA *= alA;
      const float txB = max_half64(tmB);
      const float mnB = fmaxf(mB, txB);
      const float alB = exp2_fast((mB - mnB) * SCL);
      mB = mnB; lB *= alB;
#pragma unroll
      for (int r = 0; r < 16; ++r) {
        oaA0[r] *= alA; oaA1[r] *= alA;
        oaB0[r] *= alB; oaB1[r] *= alB;
      }
    }
    const float mscA = mA * SCL, mscB = mB * SCL;
#pragma unroll
    for (int r = 0; r < 16; ++r) sA[r] = exp2_fast(fmaf(sA[r], SCL, -mscA));
#pragma unroll
    for (int r = 0; r < 16; ++r) sB[r] = exp2_fast(fmaf(sB[r], SCL, -mscB));

    // per-lane partial row-sums (cross-half combine deferred to the end)
    {
      float u[8];
#pragma unroll
      for (int r = 0; r < 8; ++r) u[r] = sA[r] + sA[r + 8];
#pragma unroll
      for (int r = 0; r < 4; ++r) u[r] += u[r + 4];
      lA += (u[0] + u[2]) + (u[1] + u[3]);
#pragma unroll
      for (int r = 0; r < 8; ++r) u[r] = sB[r] + sB[r + 8];
#pragma unroll
      for (int r = 0; r < 4; ++r) u[r] += u[r + 4];
      lB += (u[0] + u[2]) + (u[1] + u[3]);
    }

    // P -> B-fragments in-register: cvt_pk + permlane32_swap (T12)
    unsigned pwA[2][4], pwB[2][4];
#pragma unroll
    for (int kh = 0; kh < 2; ++kh) {
      {
        unsigned x0 = cvt_pk_bf16(sA[kh * 8 + 0], sA[kh * 8 + 1]);
        unsigned y0 = cvt_pk_bf16(sA[kh * 8 + 4], sA[kh * 8 + 5]);
        asm volatile("s_nop 0\n\tv_permlane32_swap_b32 %0, %1" : "+v"(x0), "+v"(y0));
        unsigned x1 = cvt_pk_bf16(sA[kh * 8 + 2], sA[kh * 8 + 3]);
        unsigned y1 = cvt_pk_bf16(sA[kh * 8 + 6], sA[kh * 8 + 7]);
        asm volatile("s_nop 0\n\tv_permlane32_swap_b32 %0, %1" : "+v"(x1), "+v"(y1));
        pwA[kh][0] = x0; pwA[kh][1] = x1; pwA[kh][2] = y0; pwA[kh][3] = y1;
      }
      {
        unsigned x0 = cvt_pk_bf16(sB[kh * 8 + 0], sB[kh * 8 + 1]);
        unsigned y0 = cvt_pk_bf16(sB[kh * 8 + 4], sB[kh * 8 + 5]);
        asm volatile("s_nop 0\n\tv_permlane32_swap_b32 %0, %1" : "+v"(x0), "+v"(y0));
        unsigned x1 = cvt_pk_bf16(sB[kh * 8 + 2], sB[kh * 8 + 3]);
        unsigned y1 = cvt_pk_bf16(sB[kh * 8 + 6], sB[kh * 8 + 7]);
        asm volatile("s_nop 0\n\tv_permlane32_swap_b32 %0, %1" : "+v"(x1), "+v"(y1));
        pwB[kh][0] = x0; pwB[kh][1] = x1; pwB[kh][2] = y0; pwB[kh][3] = y1;
      }
    }

    // O^T += V^T P^T (V frags shared across subtiles)
    __builtin_amdgcn_s_setprio(1);
#pragma unroll
    for (int kh = 0; kh < 2; ++kh) {
      union { unsigned u[4]; short8 s8; } ua, ub;
      ua.u[0] = pwA[kh][0]; ua.u[1] = pwA[kh][1]; ua.u[2] = pwA[kh][2]; ua.u[3] = pwA[kh][3];
      ub.u[0] = pwB[kh][0]; ub.u[1] = pwB[kh][1]; ub.u[2] = pwB[kh][2]; ub.u[3] = pwB[kh][3];
      {
        const int unit = ((0 * 4 + kh * 2 + l1) ^ (l31 & 7));
        short8 vf = *(const short8*)&Vb[l31 * 64 + unit * 8];
        oaA0 = __builtin_amdgcn_mfma_f32_32x32x16_bf16(vf, ua.s8, oaA0, 0, 0, 0);
        oaB0 = __builtin_amdgcn_mfma_f32_32x32x16_bf16(vf, ub.s8, oaB0, 0, 0, 0);
      }
      {
        const int unit = ((1 * 4 + kh * 2 + l1) ^ (l31 & 7));
        short8 vf = *(const short8*)&Vb[l31 * 64 + unit * 8];
        oaA1 = __builtin_amdgcn_mfma_f32_32x32x16_bf16(vf, ua.s8, oaA1, 0, 0, 0);
        oaB1 = __builtin_amdgcn_mfma_f32_32x32x16_bf16(vf, ub.s8, oaB1, 0, 0, 0);
      }
    }
    __builtin_amdgcn_s_setprio(0);
  }

  // finalize per-lane l across the two lane-halves (m already ballot-consistent)
  lA += __shfl_xor(lA, 32, 64);
  lB += __shfl_xor(lB, 32, 64);

  // ---- 2-round tree merge of the 4 KV-quarter partials, then store ----
  float* Oex = (float*)SM;                   // 4 slots x 4096 floats (64 q x 64 d)
  float* mex = ((float*)SM) + 16384;         // 4 slots x 256 floats {mA,lA,mB,lB}/lane

  auto writeSlot = [&](int s) {
    float* ob = Oex + s * 4096;
#pragma unroll
    for (int r = 0; r < 16; ++r) {
      ob[r * 64 + lane] = oaA0[r];
      ob[(16 + r) * 64 + lane] = oaA1[r];
      ob[(32 + r) * 64 + lane] = oaB0[r];
      ob[(48 + r) * 64 + lane] = oaB1[r];
    }
    float4 ml = {mA, lA, mB, lB};
    *(float4*)&mex[s * 256 + lane * 4] = ml;
  };
  auto mergeSlot = [&](int s) {
    const float4 ml = *(const float4*)&mex[s * 256 + lane * 4];
    const float* ob = Oex + s * 4096;
    {
      const float mm = fmaxf(mA, ml.x);
      const float a = exp2_fast((mA - mm) * SCL);
      const float b = exp2_fast((ml.x - mm) * SCL);
      mA = mm; lA = lA * a + ml.y * b;
#pragma unroll
      for (int r = 0; r < 16; ++r) {
        oaA0[r] = oaA0[r] * a + ob[r * 64 + lane] * b;
        oaA1[r] = oaA1[r] * a + ob[(16 + r) * 64 + lane] * b;
      }
    }
    {
      const float mm = fmaxf(mB, ml.z);
      const float a = exp2_fast((mB - mm) * SCL);
      const float b = exp2_fast((ml.z - mm) * SCL);
      mB = mm; lB = lB * a + ml.w * b;
#pragma unroll
      for (int r = 0; r < 16; ++r) {
        oaB0[r] = oaB0[r] * a + ob[(32 + r) * 64 + lane] * b;
        oaB1[r] = oaB1[r] * a + ob[(48 + r) * 64 + lane] * b;
      }
    }
  };

  __syncthreads();                           // all staging reads done; reuse SM
  if (g == 1) writeSlot(wg * 2 + 0);
  if (g == 3) writeSlot(wg * 2 + 1);
  __syncthreads();
  if (g == 0) mergeSlot(wg * 2 + 0);         // absorb quarter 1
  if (g == 2) mergeSlot(wg * 2 + 1);         // absorb quarter 3
  __syncthreads();
  if (g == 2) writeSlot(wg * 2 + 0);
  __syncthreads();
  if (g == 0) {
    mergeSlot(wg * 2 + 0);                   // absorb quarters 2+3
    const float rlA = 1.0f / lA;
    const float rlB = 1.0f / lB;
    const size_t ybA = (size_t)(q0 + wg * 64 + l31) * C_DIM + h * 64;
    const size_t ybB = (size_t)(q0 + wg * 64 + 32 + l31) * C_DIM + h * 64;
#pragma unroll
    for (int g4 = 0; g4 < 4; ++g4) {
      short4v oA0, oA1, oB0, oB1;
#pragma unroll
      for (int j = 0; j < 4; ++j) {
        oA0[j] = f2bf(oaA0[g4 * 4 + j] * rlA);
        oA1[j] = f2bf(oaA1[g4 * 4 + j] * rlA);
        oB0[j] = f2bf(oaB0[g4 * 4 + j] * rlB);
        oB1[j] = f2bf(oaB1[g4 * 4 + j] * rlB);
      }
      *(short4v*)&y[ybA + g4 * 8 + l1 * 4] = oA0;
      *(short4v*)&y[ybA + 32 + g4 * 8 + l1 * 4] = oA1;
      *(short4v*)&y[ybB + g4 * 8 + l1 * 4] = oB0;
      *(short4v*)&y[ybB + 32 + g4 * 8 + l1 * 4] = oB1;
    }
  }
}

extern "C" void kernel_launch(void* const* d_in, const int* in_sizes, int n_in,
                              void* d_out, int out_size, void* d_ws, size_t ws_size,
                              hipStream_t stream) {
  const float* x = (const float*)d_in[0];       // [T, C]
  const float* w_qkv = (const float*)d_in[1];   // [C, 3C]
  const float* w_out = (const float*)d_in[2];   // [C, C]
  float* out = (float*)d_out;                   // [T, C] fp32

  char* ws = (char*)d_ws;
  short* xb = (short*)ws;            ws += (size_t)T_SEQ * C_DIM * 2;       // 8 MB
  short* wqT = (short*)ws;           ws += (size_t)C3 * C_DIM * 2;          // 6 MB
  short* woT = (short*)ws;           ws += (size_t)C_DIM * C_DIM * 2;       // 2 MB
  short* qkv = (short*)ws;           ws += (size_t)T_SEQ * C3 * 2;          // 24 MB
  short* vT = (short*)ws;            ws += (size_t)NH * T_SEQ * HD * 2;     // 8 MB
  short* y = (short*)ws;             ws += (size_t)T_SEQ * C_DIM * 2;       // 8 MB

  // 1. convert inputs to bf16 (weights transposed to [N][K]; one fused launch)
  conv_bf16_kernel<<<(T_SEQ * C_DIM) / (256 * 8), 256, 0, stream>>>(x, xb);
  trans_conv2_kernel<<<dim3(C3 / 32 + C_DIM / 32, C_DIM / 32), dim3(32, 8), 0, stream>>>(
      w_qkv, wqT, w_out, woT);

  // 2. qkv = x @ w_qkv (bf16 out); V-columns (>=2048) written transposed into vT
  gemm_bt_kernel<<<dim3(C3 / 128, T_SEQ / 128), 256, 0, stream>>>(xb, wqT, qkv, vT, 2048,
                                                                  T_SEQ, C3, C_DIM);

  // 3. flash attention -> y [T, C] bf16 (4-way KV split)
  attn_kernel<<<512, 512, 0, stream>>>(qkv, vT, y);

  // 4. out = y @ w_out (fp32 out), 128x64 tiles -> 512 blocks = 2/CU
  gemm_bt64_kernel<<<dim3(C_DIM / 64, T_SEQ / 128), 256, 0, stream>>>(y, woT, out,
                                                                      T_SEQ, C_DIM, C_DIM);
}

// Round 17
// 171.351 us; speedup vs baseline: 1.7783x; 1.7783x over previous
//
#include <hip/hip_runtime.h>
#include <hip/hip_bf16.h>

// Sizes for this problem
#define T_SEQ 4096
#define C_DIM 1024
#define NH    16
#define HD    64
#define C3    3072

typedef __attribute__((ext_vector_type(8))) short short8;
typedef __attribute__((ext_vector_type(4))) short short4v;
typedef __attribute__((ext_vector_type(4))) float f32x4;
typedef __attribute__((ext_vector_type(16))) float f32x16;

__device__ __forceinline__ short f2bf(float f) {
  union { float f; unsigned u; } v; v.f = f;
  unsigned r = v.u + 0x7FFFu + ((v.u >> 16) & 1u);   // round-to-nearest-even
  return (short)(r >> 16);
}

__device__ __forceinline__ unsigned cvt_pk_bf16(float lo, float hi) {
  unsigned r;
  asm volatile("v_cvt_pk_bf16_f32 %0, %1, %2" : "=v"(r) : "v"(lo), "v"(hi));
  return r;
}

// single-instruction 2^x (exp2f w/o fast-math is a multi-inst ocml call)
__device__ __forceinline__ float exp2_fast(float x) {
  return __builtin_amdgcn_exp2f(x);
}

// cross-half (lane^32) max via ds_bpermute-based shfl (proven correct here;
// permlane32_swap-based reduce failed twice — suspected wait-state hazard).
__device__ __forceinline__ float max_half64(float v) {
  return fmaxf(v, __shfl_xor(v, 32, 64));
}

__device__ __forceinline__ float m3(float a, float b, float c) {
  return fmaxf(fmaxf(a, b), c);   // clang fuses to v_max3_f32
}

__device__ __forceinline__ void gld_lds16(const void* g, void* l) {
  __builtin_amdgcn_global_load_lds(
      (const __attribute__((address_space(1))) unsigned int*)g,
      (__attribute__((address_space(3))) unsigned int*)l, 16, 0, 0);
}

// ---------------- fp32 -> bf16 convert (x) ----------------
__global__ __launch_bounds__(256) void conv_bf16_kernel(const float* __restrict__ in,
                                                        short* __restrict__ out) {
  const size_t i = ((size_t)blockIdx.x * 256 + threadIdx.x) * 8;
  float4 v0 = *(const float4*)(in + i);
  float4 v1 = *(const float4*)(in + i + 4);
  short8 o;
  o[0] = f2bf(v0.x); o[1] = f2bf(v0.y); o[2] = f2bf(v0.z); o[3] = f2bf(v0.w);
  o[4] = f2bf(v1.x); o[5] = f2bf(v1.y); o[6] = f2bf(v1.z); o[7] = f2bf(v1.w);
  *(short8*)(out + i) = o;
}

// ---------------- both weights: fp32 [K][N] -> bf16 [N][K] transpose-convert ----------------
__global__ void trans_conv2_kernel(const float* __restrict__ wq, short* __restrict__ wqT,
                                   const float* __restrict__ wo, short* __restrict__ woT) {
  const float* in;
  short* out;
  int N, bx = blockIdx.x;
  if (bx < C3 / 32) { in = wq; out = wqT; N = C3; }
  else              { in = wo; out = woT; N = C_DIM; bx -= C3 / 32; }
  const int K = C_DIM;
  __shared__ float t[32][33];
  const int n0 = bx * 32, k0 = blockIdx.y * 32;
  const int tx = threadIdx.x, ty = threadIdx.y;
  for (int i = ty; i < 32; i += 8) t[i][tx] = in[(size_t)(k0 + i) * N + n0 + tx];
  __syncthreads();
  for (int i = ty; i < 32; i += 8) out[(size_t)(n0 + i) * K + k0 + tx] = f2bf(t[tx][i]);
}

// ---------------- bf16 GEMM: C[M,N] = A[M,K] * BT[N,K]^T (128x128 tile) ----------------
// Blocks with bn >= vcol0 write their tile TRANSPOSED into vTout[(col-vcol0)*M + row]
__global__ __launch_bounds__(256) void gemm_bt_kernel(const short* __restrict__ A,
                                                      const short* __restrict__ BT,
                                                      short* __restrict__ C,
                                                      short* __restrict__ vTout,
                                                      int vcol0,
                                                      int M, int N, int K) {
  __shared__ __align__(16) short As[128 * 32];
  __shared__ __align__(16) short Bs[128 * 32];
  const int tid = threadIdx.x;
  const int wid = tid >> 6;
  const int lane = tid & 63;
  const int l15 = lane & 15;
  const int l4 = lane >> 4;
  const int wr = wid >> 1;
  const int wc = wid & 1;

  // XCD-aware bijective swizzle (grid count divisible by 8)
  const int nwg = gridDim.x * gridDim.y;
  int lin = blockIdx.y * gridDim.x + blockIdx.x;
  lin = (lin & 7) * (nwg >> 3) + (lin >> 3);
  const int bm = (lin / gridDim.x) * 128;
  const int bn = (lin % gridDim.x) * 128;

  f32x4 acc[4][4];
#pragma unroll
  for (int m = 0; m < 4; ++m)
#pragma unroll
    for (int n = 0; n < 4; ++n) acc[m][n] = (f32x4){0.f, 0.f, 0.f, 0.f};

  const int ebase = wid * 1024;              // 1024 bf16 elements per wave (2 x 512)
  const int e0 = ebase + lane * 8;
  const int r0 = e0 >> 5, c0 = e0 & 31;
  const int r1 = r0 + 16;                    // e0 + 512

  for (int k0 = 0; k0 < K; k0 += 32) {
    __syncthreads();
    gld_lds16(A + (size_t)(bm + r0) * K + k0 + c0, As + ebase);
    gld_lds16(A + (size_t)(bm + r1) * K + k0 + c0, As + ebase + 512);
    gld_lds16(BT + (size_t)(bn + r0) * K + k0 + c0, Bs + ebase);
    gld_lds16(BT + (size_t)(bn + r1) * K + k0 + c0, Bs + ebase + 512);
    __syncthreads();

    short8 a[4], b[4];
#pragma unroll
    for (int m = 0; m < 4; ++m)
      a[m] = *(const short8*)&As[(wr * 64 + m * 16 + l15) * 32 + l4 * 8];
#pragma unroll
    for (int n = 0; n < 4; ++n)
      b[n] = *(const short8*)&Bs[(wc * 64 + n * 16 + l15) * 32 + l4 * 8];
#pragma unroll
    for (int m = 0; m < 4; ++m)
#pragma unroll
      for (int n = 0; n < 4; ++n)
        acc[m][n] = __builtin_amdgcn_mfma_f32_16x16x32_bf16(a[m], b[n], acc[m][n], 0, 0, 0);
  }

  if (bn >= vcol0) {
#pragma unroll
    for (int m = 0; m < 4; ++m) {
      const int row0 = bm + wr * 64 + m * 16 + l4 * 4;
#pragma unroll
      for (int n = 0; n < 4; ++n) {
        const int col = bn + wc * 64 + n * 16 + l15;
        short4v o;
#pragma unroll
        for (int r = 0; r < 4; ++r) o[r] = f2bf(acc[m][n][r]);
        *(short4v*)&vTout[(size_t)(col - vcol0) * M + row0] = o;
      }
    }
  } else {
#pragma unroll
    for (int m = 0; m < 4; ++m) {
      const int row0 = bm + wr * 64 + m * 16 + l4 * 4;
#pragma unroll
      for (int n = 0; n < 4; ++n) {
        const int col = bn + wc * 64 + n * 16 + l15;
#pragma unroll
        for (int r = 0; r < 4; ++r)
          C[(size_t)(row0 + r) * N + col] = f2bf(acc[m][n][r]);
      }
    }
  }
}

// ---------------- bf16 GEMM: 128x64 tile, fp32 out (GEMM2: 2 blocks/CU) ----------------
__global__ __launch_bounds__(256) void gemm_bt64_kernel(const short* __restrict__ A,
                                                        const short* __restrict__ BT,
                                                        float* __restrict__ C,
                                                        int M, int N, int K) {
  __shared__ __align__(16) short As[128 * 32];
  __shared__ __align__(16) short Bs[64 * 32];
  const int tid = threadIdx.x;
  const int wid = tid >> 6;
  const int lane = tid & 63;
  const int l15 = lane & 15;
  const int l4 = lane >> 4;
  const int wr = wid >> 1;
  const int wc = wid & 1;

  const int nwg = gridDim.x * gridDim.y;
  int lin = blockIdx.y * gridDim.x + blockIdx.x;
  lin = (lin & 7) * (nwg >> 3) + (lin >> 3);
  const int bm = (lin / gridDim.x) * 128;
  const int bn = (lin % gridDim.x) * 64;

  f32x4 acc[4][2];
#pragma unroll
  for (int m = 0; m < 4; ++m)
#pragma unroll
    for (int n = 0; n < 2; ++n) acc[m][n] = (f32x4){0.f, 0.f, 0.f, 0.f};

  const int ebase = wid * 1024;
  const int e0 = ebase + lane * 8;
  const int r0 = e0 >> 5, c0 = e0 & 31;
  const int r1 = r0 + 16;
  const int eb = wid * 512 + lane * 8;
  const int rb = eb >> 5, cb = eb & 31;

  for (int k0 = 0; k0 < K; k0 += 32) {
    __syncthreads();
    gld_lds16(A + (size_t)(bm + r0) * K + k0 + c0, As + ebase);
    gld_lds16(A + (size_t)(bm + r1) * K + k0 + c0, As + ebase + 512);
    gld_lds16(BT + (size_t)(bn + rb) * K + k0 + cb, Bs + eb);
    __syncthreads();

    short8 a[4], b[2];
#pragma unroll
    for (int m = 0; m < 4; ++m)
      a[m] = *(const short8*)&As[(wr * 64 + m * 16 + l15) * 32 + l4 * 8];
#pragma unroll
    for (int n = 0; n < 2; ++n)
      b[n] = *(const short8*)&Bs[(wc * 32 + n * 16 + l15) * 32 + l4 * 8];
#pragma unroll
    for (int m = 0; m < 4; ++m)
#pragma unroll
      for (int n = 0; n < 2; ++n)
        acc[m][n] = __builtin_amdgcn_mfma_f32_16x16x32_bf16(a[m], b[n], acc[m][n], 0, 0, 0);
  }

#pragma unroll
  for (int m = 0; m < 4; ++m) {
    const int row0 = bm + wr * 64 + m * 16 + l4 * 4;
#pragma unroll
    for (int n = 0; n < 2; ++n) {
      const int col = bn + wc * 32 + n * 16 + l15;
#pragma unroll
      for (int r = 0; r < 4; ++r)
        C[(size_t)(row0 + r) * N + col] = acc[m][n][r];
    }
  }
}

// ---------------- flash attention: 4-way KV split (chain 1024), 64 q per wave ----------------
// 512 blocks x 512 threads = 8 waves: group g = w>>1 covers KV quarter g; wg = w&1
// selects 64 q rows. NOTE: plain __launch_bounds__(512) — the (512,4) variant forced
// VGPR=64 and spilled to scratch (FETCH 689 MB). NT = 32; 2-round tree merge at end.
__global__ __launch_bounds__(512) void attn_kernel(const short* __restrict__ qkv,
                                                   const short* __restrict__ vT,
                                                   short* __restrict__ y) {
  // XCD-aware: heads {2x, 2x+1} -> XCD x (round-robin bid%8 assumption)
  const int bid = blockIdx.x;
  const int xcd = bid & 7, slot = bid >> 3;      // slot 0..63
  const int h = xcd * 2 + (slot >> 5);
  const int q0 = (slot & 31) * 128;

  const int tid = threadIdx.x;
  const int w = tid >> 6, lane = tid & 63, l31 = lane & 31, l1 = lane >> 5;
  const int g = w >> 1, wg = w & 1;              // group = KV quarter; wg = q-wave
  const int kvbase = g * (T_SEQ / 4);

  // 68 KB shared: [0,16384) shorts = K staging (4 grp x 2 buf x 2048),
  // [16384,32768) = V staging; merge Oex/mex (4 slots x 16KB + ml) overlays after.
  __shared__ __align__(16) short SM[34816];

  // Q B-fragments: subtile A = q0+wg*64+l31, B = +32; k = d = ks*16 + l1*8 + j
  short8 qfA[4], qfB[4];
  {
    const short* qp = qkv + (size_t)(q0 + wg * 64 + l31) * C3 + h * 64 + l1 * 8;
#pragma unroll
    for (int ks = 0; ks < 4; ++ks) {
      qfA[ks] = *(const short8*)(qp + ks * 16);
      qfB[ks] = *(const short8*)(qp + (size_t)32 * C3 + ks * 16);
    }
  }

  f32x16 oaA0, oaA1, oaB0, oaB1;   // O^T: col q=l31, row d=(r&3)+8*(r>>2)+4*l1 (+32 for *1)
#pragma unroll
  for (int r = 0; r < 16; ++r) { oaA0[r] = 0.f; oaA1[r] = 0.f; oaB0[r] = 0.f; oaB1[r] = 0.f; }
  float mA = -INFINITY, lA = 0.f, mB = -INFINITY, lB = 0.f;
  const float SCL = 0.125f * 1.44269504f;          // 1/sqrt(64) * log2(e)
  const float TH = 8.0f / SCL;                     // defer-max threshold (p <= 2^8)

  // staging pointers (wave-load i covers 8 rows; rows = wg*16 + i*8 + (lane>>3))
  const int csw = ((lane & 7) << 3) ^ ((lane >> 3) << 3);
  const short* kpt = qkv + 1024 + h * 64 + csw +
                     (size_t)(kvbase + wg * 16 + (lane >> 3)) * C3;
  const int lu = (lane & 7) ^ (lane >> 3);
  const short* vpt = vT + (size_t)(h * 64 + wg * 16 + (lane >> 3) + (lu >> 2) * 32) * T_SEQ +
                     kvbase + (lu & 3) * 8;
  const int rswz = (l31 & 7) << 3;

  short* const Kbase = SM + g * 4096;
  short* const Vbase = SM + 16384 + g * 4096;

  auto stage = [&](int buf) {
#pragma unroll
    for (int i = 0; i < 2; ++i) {
      gld_lds16(kpt + (size_t)i * 8 * C3, Kbase + buf * 2048 + wg * 1024 + i * 512);
      gld_lds16(vpt + (size_t)i * 8 * T_SEQ, Vbase + buf * 2048 + wg * 1024 + i * 512);
    }
  };

  stage(0);
  kpt += (size_t)32 * C3;
  vpt += 32;

  const int NT = (T_SEQ / 4) / 32;   // 32 tiles per quarter
  for (int t = 0; t < NT; ++t) {
    const int cur = t & 1;
    __builtin_amdgcn_s_barrier();            // done reading buf cur^1
    if (t + 1 < NT) {
      stage(cur ^ 1);
      kpt += (size_t)32 * C3;
      vpt += 32;
      asm volatile("s_waitcnt vmcnt(4)" ::: "memory");   // tile-t loads landed; t+1's fly
    } else {
      asm volatile("s_waitcnt vmcnt(0)" ::: "memory");
    }
    __builtin_amdgcn_s_barrier();            // tile-t data visible

    const short* Kb = Kbase + cur * 2048;
    const short* Vb = Vbase + cur * 2048;

    // S^T = K Q^T for both q-subtiles (K frags shared)
    f32x16 sA, sB;
#pragma unroll
    for (int r = 0; r < 16; ++r) { sA[r] = 0.f; sB[r] = 0.f; }
    __builtin_amdgcn_s_setprio(1);
#pragma unroll
    for (int ks = 0; ks < 4; ++ks) {
      const int c = (ks * 16 + l1 * 8) ^ rswz;
      short8 kf = *(const short8*)&Kb[l31 * 64 + c];
      sA = __builtin_amdgcn_mfma_f32_32x32x16_bf16(kf, qfA[ks], sA, 0, 0, 0);
      sB = __builtin_amdgcn_mfma_f32_32x32x16_bf16(kf, qfB[ks], sB, 0, 0, 0);
    }
    __builtin_amdgcn_s_setprio(0);

    // lane-local maxes via max3 trees
    float tmA, tmB;
    {
      float v0 = m3(sA[0], sA[1], sA[2]);
      float v1 = m3(sA[3], sA[4], sA[5]);
      float v2 = m3(sA[6], sA[7], sA[8]);
      float v3 = m3(sA[9], sA[10], sA[11]);
      float v4 = m3(sA[12], sA[13], sA[14]);
      tmA = fmaxf(m3(v0, v1, v2), m3(v3, v4, sA[15]));
      float u0 = m3(sB[0], sB[1], sB[2]);
      float u1 = m3(sB[3], sB[4], sB[5]);
      float u2 = m3(sB[6], sB[7], sB[8]);
      float u3 = m3(sB[9], sB[10], sB[11]);
      float u4 = m3(sB[12], sB[13], sB[14]);
      tmB = fmaxf(m3(u0, u1, u2), m3(u3, u4, sB[15]));
    }

    // defer-max: single 64-lane ballot for both subtiles keeps halves consistent
    if (__any(fmaxf(tmA - mA, tmB - mB) > TH)) {
      const float txA = max_half64(tmA);
      const float mnA = fmaxf(mA, txA);
      const float alA = exp2_fast((mA - mnA) * SCL);
      mA = mnA; lA *= alA;
      const float txB = max_half64(tmB);
      const float mnB = fmaxf(mB, txB);
      const float alB = exp2_fast((mB - mnB) * SCL);
      mB = mnB; lB *= alB;
#pragma unroll
      for (int r = 0; r < 16; ++r) {
        oaA0[r] *= alA; oaA1[r] *= alA;
        oaB0[r] *= alB; oaB1[r] *= alB;
      }
    }
    const float mscA = mA * SCL, mscB = mB * SCL;
#pragma unroll
    for (int r = 0; r < 16; ++r) sA[r] = exp2_fast(fmaf(sA[r], SCL, -mscA));
#pragma unroll
    for (int r = 0; r < 16; ++r) sB[r] = exp2_fast(fmaf(sB[r], SCL, -mscB));

    // per-lane partial row-sums (cross-half combine deferred to the end)
    {
      float u[8];
#pragma unroll
      for (int r = 0; r < 8; ++r) u[r] = sA[r] + sA[r + 8];
#pragma unroll
      for (int r = 0; r < 4; ++r) u[r] += u[r + 4];
      lA += (u[0] + u[2]) + (u[1] + u[3]);
#pragma unroll
      for (int r = 0; r < 8; ++r) u[r] = sB[r] + sB[r + 8];
#pragma unroll
      for (int r = 0; r < 4; ++r) u[r] += u[r + 4];
      lB += (u[0] + u[2]) + (u[1] + u[3]);
    }

    // P -> B-fragments in-register: cvt_pk + permlane32_swap (T12)
    unsigned pwA[2][4], pwB[2][4];
#pragma unroll
    for (int kh = 0; kh < 2; ++kh) {
      {
        unsigned x0 = cvt_pk_bf16(sA[kh * 8 + 0], sA[kh * 8 + 1]);
        unsigned y0 = cvt_pk_bf16(sA[kh * 8 + 4], sA[kh * 8 + 5]);
        asm volatile("s_nop 0\n\tv_permlane32_swap_b32 %0, %1" : "+v"(x0), "+v"(y0));
        unsigned x1 = cvt_pk_bf16(sA[kh * 8 + 2], sA[kh * 8 + 3]);
        unsigned y1 = cvt_pk_bf16(sA[kh * 8 + 6], sA[kh * 8 + 7]);
        asm volatile("s_nop 0\n\tv_permlane32_swap_b32 %0, %1" : "+v"(x1), "+v"(y1));
        pwA[kh][0] = x0; pwA[kh][1] = x1; pwA[kh][2] = y0; pwA[kh][3] = y1;
      }
      {
        unsigned x0 = cvt_pk_bf16(sB[kh * 8 + 0], sB[kh * 8 + 1]);
        unsigned y0 = cvt_pk_bf16(sB[kh * 8 + 4], sB[kh * 8 + 5]);
        asm volatile("s_nop 0\n\tv_permlane32_swap_b32 %0, %1" : "+v"(x0), "+v"(y0));
        unsigned x1 = cvt_pk_bf16(sB[kh * 8 + 2], sB[kh * 8 + 3]);
        unsigned y1 = cvt_pk_bf16(sB[kh * 8 + 6], sB[kh * 8 + 7]);
        asm volatile("s_nop 0\n\tv_permlane32_swap_b32 %0, %1" : "+v"(x1), "+v"(y1));
        pwB[kh][0] = x0; pwB[kh][1] = x1; pwB[kh][2] = y0; pwB[kh][3] = y1;
      }
    }

    // O^T += V^T P^T (V frags shared across subtiles)
    __builtin_amdgcn_s_setprio(1);
#pragma unroll
    for (int kh = 0; kh < 2; ++kh) {
      union { unsigned u[4]; short8 s8; } ua, ub;
      ua.u[0] = pwA[kh][0]; ua.u[1] = pwA[kh][1]; ua.u[2] = pwA[kh][2]; ua.u[3] = pwA[kh][3];
      ub.u[0] = pwB[kh][0]; ub.u[1] = pwB[kh][1]; ub.u[2] = pwB[kh][2]; ub.u[3] = pwB[kh][3];
      {
        const int unit = ((0 * 4 + kh * 2 + l1) ^ (l31 & 7));
        short8 vf = *(const short8*)&Vb[l31 * 64 + unit * 8];
        oaA0 = __builtin_amdgcn_mfma_f32_32x32x16_bf16(vf, ua.s8, oaA0, 0, 0, 0);
        oaB0 = __builtin_amdgcn_mfma_f32_32x32x16_bf16(vf, ub.s8, oaB0, 0, 0, 0);
      }
      {
        const int unit = ((1 * 4 + kh * 2 + l1) ^ (l31 & 7));
        short8 vf = *(const short8*)&Vb[l31 * 64 + unit * 8];
        oaA1 = __builtin_amdgcn_mfma_f32_32x32x16_bf16(vf, ua.s8, oaA1, 0, 0, 0);
        oaB1 = __builtin_amdgcn_mfma_f32_32x32x16_bf16(vf, ub.s8, oaB1, 0, 0, 0);
      }
    }
    __builtin_amdgcn_s_setprio(0);
  }

  // finalize per-lane l across the two lane-halves (m already ballot-consistent)
  lA += __shfl_xor(lA, 32, 64);
  lB += __shfl_xor(lB, 32, 64);

  // ---- 2-round tree merge of the 4 KV-quarter partials, then store ----
  float* Oex = (float*)SM;                   // 4 slots x 4096 floats (64 q x 64 d)
  float* mex = ((float*)SM) + 16384;         // 4 slots x 256 floats {mA,lA,mB,lB}/lane

  auto writeSlot = [&](int s) {
    float* ob = Oex + s * 4096;
#pragma unroll
    for (int r = 0; r < 16; ++r) {
      ob[r * 64 + lane] = oaA0[r];
      ob[(16 + r) * 64 + lane] = oaA1[r];
      ob[(32 + r) * 64 + lane] = oaB0[r];
      ob[(48 + r) * 64 + lane] = oaB1[r];
    }
    float4 ml = {mA, lA, mB, lB};
    *(float4*)&mex[s * 256 + lane * 4] = ml;
  };
  auto mergeSlot = [&](int s) {
    const float4 ml = *(const float4*)&mex[s * 256 + lane * 4];
    const float* ob = Oex + s * 4096;
    {
      const float mm = fmaxf(mA, ml.x);
      const float a = exp2_fast((mA - mm) * SCL);
      const float b = exp2_fast((ml.x - mm) * SCL);
      mA = mm; lA = lA * a + ml.y * b;
#pragma unroll
      for (int r = 0; r < 16; ++r) {
        oaA0[r] = oaA0[r] * a + ob[r * 64 + lane] * b;
        oaA1[r] = oaA1[r] * a + ob[(16 + r) * 64 + lane] * b;
      }
    }
    {
      const float mm = fmaxf(mB, ml.z);
      const float a = exp2_fast((mB - mm) * SCL);
      const float b = exp2_fast((ml.z - mm) * SCL);
      mB = mm; lB = lB * a + ml.w * b;
#pragma unroll
      for (int r = 0; r < 16; ++r) {
        oaB0[r] = oaB0[r] * a + ob[(32 + r) * 64 + lane] * b;
        oaB1[r] = oaB1[r] * a + ob[(48 + r) * 64 + lane] * b;
      }
    }
  };

  __syncthreads();                           // all staging reads done; reuse SM
  if (g == 1) writeSlot(wg * 2 + 0);
  if (g == 3) writeSlot(wg * 2 + 1);
  __syncthreads();
  if (g == 0) mergeSlot(wg * 2 + 0);         // absorb quarter 1
  if (g == 2) mergeSlot(wg * 2 + 1);         // absorb quarter 3
  __syncthreads();
  if (g == 2) writeSlot(wg * 2 + 0);
  __syncthreads();
  if (g == 0) {
    mergeSlot(wg * 2 + 0);                   // absorb quarters 2+3
    const float rlA = 1.0f / lA;
    const float rlB = 1.0f / lB;
    const size_t ybA = (size_t)(q0 + wg * 64 + l31) * C_DIM + h * 64;
    const size_t ybB = (size_t)(q0 + wg * 64 + 32 + l31) * C_DIM + h * 64;
#pragma unroll
    for (int g4 = 0; g4 < 4; ++g4) {
      short4v oA0, oA1, oB0, oB1;
#pragma unroll
      for (int j = 0; j < 4; ++j) {
        oA0[j] = f2bf(oaA0[g4 * 4 + j] * rlA);
        oA1[j] = f2bf(oaA1[g4 * 4 + j] * rlA);
        oB0[j] = f2bf(oaB0[g4 * 4 + j] * rlB);
        oB1[j] = f2bf(oaB1[g4 * 4 + j] * rlB);
      }
      *(short4v*)&y[ybA + g4 * 8 + l1 * 4] = oA0;
      *(short4v*)&y[ybA + 32 + g4 * 8 + l1 * 4] = oA1;
      *(short4v*)&y[ybB + g4 * 8 + l1 * 4] = oB0;
      *(short4v*)&y[ybB + 32 + g4 * 8 + l1 * 4] = oB1;
    }
  }
}

extern "C" void kernel_launch(void* const* d_in, const int* in_sizes, int n_in,
                              void* d_out, int out_size, void* d_ws, size_t ws_size,
                              hipStream_t stream) {
  const float* x = (const float*)d_in[0];       // [T, C]
  const float* w_qkv = (const float*)d_in[1];   // [C, 3C]
  const float* w_out = (const float*)d_in[2];   // [C, C]
  float* out = (float*)d_out;                   // [T, C] fp32

  char* ws = (char*)d_ws;
  short* xb = (short*)ws;            ws += (size_t)T_SEQ * C_DIM * 2;       // 8 MB
  short* wqT = (short*)ws;           ws += (size_t)C3 * C_DIM * 2;          // 6 MB
  short* woT = (short*)ws;           ws += (size_t)C_DIM * C_DIM * 2;       // 2 MB
  short* qkv = (short*)ws;           ws += (size_t)T_SEQ * C3 * 2;          // 24 MB
  short* vT = (short*)ws;            ws += (size_t)NH * T_SEQ * HD * 2;     // 8 MB
  short* y = (short*)ws;             ws += (size_t)T_SEQ * C_DIM * 2;       // 8 MB

  // 1. convert inputs to bf16 (weights transposed to [N][K]; one fused launch)
  conv_bf16_kernel<<<(T_SEQ * C_DIM) / (256 * 8), 256, 0, stream>>>(x, xb);
  trans_conv2_kernel<<<dim3(C3 / 32 + C_DIM / 32, C_DIM / 32), dim3(32, 8), 0, stream>>>(
      w_qkv, wqT, w_out, woT);

  // 2. qkv = x @ w_qkv (bf16 out); V-columns (>=2048) written transposed into vT
  gemm_bt_kernel<<<dim3(C3 / 128, T_SEQ / 128), 256, 0, stream>>>(xb, wqT, qkv, vT, 2048,
                                                                  T_SEQ, C3, C_DIM);

  // 3. flash attention -> y [T, C] bf16 (4-way KV split)
  attn_kernel<<<512, 512, 0, stream>>>(qkv, vT, y);

  // 4. out = y @ w_out (fp32 out), 128x64 tiles -> 512 blocks = 2/CU
  gemm_bt64_kernel<<<dim3(C_DIM / 64, T_SEQ / 128), 256, 0, stream>>>(y, woT, out,
                                                                      T_SEQ, C_DIM, C_DIM);
}

// Round 18
// 164.539 us; speedup vs baseline: 1.8519x; 1.0414x over previous
//
#include <hip/hip_runtime.h>
#include <hip/hip_bf16.h>

// Sizes for this problem
#define T_SEQ 4096
#define C_DIM 1024
#define NH    16
#define HD    64
#define C3    3072

typedef __attribute__((ext_vector_type(8))) short short8;
typedef __attribute__((ext_vector_type(4))) short short4v;
typedef __attribute__((ext_vector_type(4))) float f32x4;
typedef __attribute__((ext_vector_type(16))) float f32x16;

__device__ __forceinline__ short f2bf(float f) {
  union { float f; unsigned u; } v; v.f = f;
  unsigned r = v.u + 0x7FFFu + ((v.u >> 16) & 1u);   // round-to-nearest-even
  return (short)(r >> 16);
}

__device__ __forceinline__ unsigned cvt_pk_bf16(float lo, float hi) {
  unsigned r;
  asm volatile("v_cvt_pk_bf16_f32 %0, %1, %2" : "=v"(r) : "v"(lo), "v"(hi));
  return r;
}

// single-instruction 2^x (exp2f w/o fast-math is a multi-inst ocml call)
__device__ __forceinline__ float exp2_fast(float x) {
  return __builtin_amdgcn_exp2f(x);
}

// cross-half (lane^32) max via ds_bpermute-based shfl (proven correct here;
// permlane32_swap-based reduce failed twice — suspected wait-state hazard).
__device__ __forceinline__ float max_half64(float v) {
  return fmaxf(v, __shfl_xor(v, 32, 64));
}

__device__ __forceinline__ float m3(float a, float b, float c) {
  return fmaxf(fmaxf(a, b), c);   // clang fuses to v_max3_f32
}

__device__ __forceinline__ void gld_lds16(const void* g, void* l) {
  __builtin_amdgcn_global_load_lds(
      (const __attribute__((address_space(1))) unsigned int*)g,
      (__attribute__((address_space(3))) unsigned int*)l, 16, 0, 0);
}

// ---------------- fp32 -> bf16 convert (x) ----------------
__global__ __launch_bounds__(256) void conv_bf16_kernel(const float* __restrict__ in,
                                                        short* __restrict__ out) {
  const size_t i = ((size_t)blockIdx.x * 256 + threadIdx.x) * 8;
  float4 v0 = *(const float4*)(in + i);
  float4 v1 = *(const float4*)(in + i + 4);
  short8 o;
  o[0] = f2bf(v0.x); o[1] = f2bf(v0.y); o[2] = f2bf(v0.z); o[3] = f2bf(v0.w);
  o[4] = f2bf(v1.x); o[5] = f2bf(v1.y); o[6] = f2bf(v1.z); o[7] = f2bf(v1.w);
  *(short8*)(out + i) = o;
}

// ---------------- both weights: fp32 [K][N] -> bf16 [N][K] transpose-convert ----------------
// gridDim.x = 96 + 32 (w_qkv cols / w_out cols); gridDim.y = 32 (K tiles)
__global__ void trans_conv2_kernel(const float* __restrict__ wq, short* __restrict__ wqT,
                                   const float* __restrict__ wo, short* __restrict__ woT) {
  const float* in;
  short* out;
  int N, bx = blockIdx.x;
  if (bx < C3 / 32) { in = wq; out = wqT; N = C3; }
  else              { in = wo; out = woT; N = C_DIM; bx -= C3 / 32; }
  const int K = C_DIM;
  __shared__ float t[32][33];
  const int n0 = bx * 32, k0 = blockIdx.y * 32;
  const int tx = threadIdx.x, ty = threadIdx.y;
  for (int i = ty; i < 32; i += 8) t[i][tx] = in[(size_t)(k0 + i) * N + n0 + tx];
  __syncthreads();
  for (int i = ty; i < 32; i += 8) out[(size_t)(n0 + i) * K + k0 + tx] = f2bf(t[tx][i]);
}

// ---------------- bf16 GEMM: C[M,N] = A[M,K] * BT[N,K]^T (128x128 tile) ----------------
// Blocks with bn >= vcol0 write their tile TRANSPOSED into vTout[(col-vcol0)*M + row]
// (bf16), fusing the V-repack into the epilogue; other blocks write C normally.
__global__ __launch_bounds__(256) void gemm_bt_kernel(const short* __restrict__ A,
                                                      const short* __restrict__ BT,
                                                      short* __restrict__ C,
                                                      short* __restrict__ vTout,
                                                      int vcol0,
                                                      int M, int N, int K) {
  __shared__ __align__(16) short As[128 * 32];
  __shared__ __align__(16) short Bs[128 * 32];
  const int tid = threadIdx.x;
  const int wid = tid >> 6;
  const int lane = tid & 63;
  const int l15 = lane & 15;
  const int l4 = lane >> 4;
  const int wr = wid >> 1;
  const int wc = wid & 1;

  // XCD-aware bijective swizzle (grid count divisible by 8)
  const int nwg = gridDim.x * gridDim.y;
  int lin = blockIdx.y * gridDim.x + blockIdx.x;
  lin = (lin & 7) * (nwg >> 3) + (lin >> 3);
  const int bm = (lin / gridDim.x) * 128;
  const int bn = (lin % gridDim.x) * 128;

  f32x4 acc[4][4];
#pragma unroll
  for (int m = 0; m < 4; ++m)
#pragma unroll
    for (int n = 0; n < 4; ++n) acc[m][n] = (f32x4){0.f, 0.f, 0.f, 0.f};

  const int ebase = wid * 1024;              // 1024 bf16 elements per wave (2 x 512)
  const int e0 = ebase + lane * 8;
  const int r0 = e0 >> 5, c0 = e0 & 31;
  const int r1 = r0 + 16;                    // e0 + 512

  for (int k0 = 0; k0 < K; k0 += 32) {
    __syncthreads();
    gld_lds16(A + (size_t)(bm + r0) * K + k0 + c0, As + ebase);
    gld_lds16(A + (size_t)(bm + r1) * K + k0 + c0, As + ebase + 512);
    gld_lds16(BT + (size_t)(bn + r0) * K + k0 + c0, Bs + ebase);
    gld_lds16(BT + (size_t)(bn + r1) * K + k0 + c0, Bs + ebase + 512);
    __syncthreads();

    short8 a[4], b[4];
#pragma unroll
    for (int m = 0; m < 4; ++m)
      a[m] = *(const short8*)&As[(wr * 64 + m * 16 + l15) * 32 + l4 * 8];
#pragma unroll
    for (int n = 0; n < 4; ++n)
      b[n] = *(const short8*)&Bs[(wc * 64 + n * 16 + l15) * 32 + l4 * 8];
#pragma unroll
    for (int m = 0; m < 4; ++m)
#pragma unroll
      for (int n = 0; n < 4; ++n)
        acc[m][n] = __builtin_amdgcn_mfma_f32_16x16x32_bf16(a[m], b[n], acc[m][n], 0, 0, 0);
  }

  if (bn >= vcol0) {
    // V-part block: vTout[(col - vcol0)][row] ; 4 consecutive rows -> one short4 store
#pragma unroll
    for (int m = 0; m < 4; ++m) {
      const int row0 = bm + wr * 64 + m * 16 + l4 * 4;
#pragma unroll
      for (int n = 0; n < 4; ++n) {
        const int col = bn + wc * 64 + n * 16 + l15;
        short4v o;
#pragma unroll
        for (int r = 0; r < 4; ++r) o[r] = f2bf(acc[m][n][r]);
        *(short4v*)&vTout[(size_t)(col - vcol0) * M + row0] = o;
      }
    }
  } else {
#pragma unroll
    for (int m = 0; m < 4; ++m) {
      const int row0 = bm + wr * 64 + m * 16 + l4 * 4;
#pragma unroll
      for (int n = 0; n < 4; ++n) {
        const int col = bn + wc * 64 + n * 16 + l15;
#pragma unroll
        for (int r = 0; r < 4; ++r)
          C[(size_t)(row0 + r) * N + col] = f2bf(acc[m][n][r]);
      }
    }
  }
}

// ---------------- bf16 GEMM: 128x64 tile, fp32 out (GEMM2: 2 blocks/CU) ----------------
__global__ __launch_bounds__(256) void gemm_bt64_kernel(const short* __restrict__ A,
                                                        const short* __restrict__ BT,
                                                        float* __restrict__ C,
                                                        int M, int N, int K) {
  __shared__ __align__(16) short As[128 * 32];
  __shared__ __align__(16) short Bs[64 * 32];
  const int tid = threadIdx.x;
  const int wid = tid >> 6;
  const int lane = tid & 63;
  const int l15 = lane & 15;
  const int l4 = lane >> 4;
  const int wr = wid >> 1;                   // 0..1 -> 64-row half
  const int wc = wid & 1;                    // 0..1 -> 32-col half

  const int nwg = gridDim.x * gridDim.y;
  int lin = blockIdx.y * gridDim.x + blockIdx.x;
  lin = (lin & 7) * (nwg >> 3) + (lin >> 3);
  const int bm = (lin / gridDim.x) * 128;
  const int bn = (lin % gridDim.x) * 64;

  f32x4 acc[4][2];
#pragma unroll
  for (int m = 0; m < 4; ++m)
#pragma unroll
    for (int n = 0; n < 2; ++n) acc[m][n] = (f32x4){0.f, 0.f, 0.f, 0.f};

  const int ebase = wid * 1024;
  const int e0 = ebase + lane * 8;
  const int r0 = e0 >> 5, c0 = e0 & 31;
  const int r1 = r0 + 16;
  const int eb = wid * 512 + lane * 8;       // B: 64x32 = 2048 elems, 512/wave
  const int rb = eb >> 5, cb = eb & 31;

  for (int k0 = 0; k0 < K; k0 += 32) {
    __syncthreads();
    gld_lds16(A + (size_t)(bm + r0) * K + k0 + c0, As + ebase);
    gld_lds16(A + (size_t)(bm + r1) * K + k0 + c0, As + ebase + 512);
    gld_lds16(BT + (size_t)(bn + rb) * K + k0 + cb, Bs + eb);
    __syncthreads();

    short8 a[4], b[2];
#pragma unroll
    for (int m = 0; m < 4; ++m)
      a[m] = *(const short8*)&As[(wr * 64 + m * 16 + l15) * 32 + l4 * 8];
#pragma unroll
    for (int n = 0; n < 2; ++n)
      b[n] = *(const short8*)&Bs[(wc * 32 + n * 16 + l15) * 32 + l4 * 8];
#pragma unroll
    for (int m = 0; m < 4; ++m)
#pragma unroll
      for (int n = 0; n < 2; ++n)
        acc[m][n] = __builtin_amdgcn_mfma_f32_16x16x32_bf16(a[m], b[n], acc[m][n], 0, 0, 0);
  }

#pragma unroll
  for (int m = 0; m < 4; ++m) {
    const int row0 = bm + wr * 64 + m * 16 + l4 * 4;
#pragma unroll
    for (int n = 0; n < 2; ++n) {
      const int col = bn + wc * 32 + n * 16 + l15;
#pragma unroll
      for (int r = 0; r < 4; ++r)
        C[(size_t)(row0 + r) * N + col] = acc[m][n][r];
    }
  }
}

// ---------------- flash attention: 64 q per wave (2 subtiles share K/V frags) ----------------
// 512 blocks x 256 threads = 4 waves: waves {0,1} q rows [q0+w*64,+64) on KV half 0;
// waves {2,3} same q on KV half 1. KVBLK=32, counted-vmcnt double-buffer, end merge via LDS.
__global__ __launch_bounds__(256, 2) void attn_kernel(const short* __restrict__ qkv,
                                                      const short* __restrict__ vT,
                                                      short* __restrict__ y) {
  // XCD-aware: heads {2x, 2x+1} -> XCD x (round-robin bid%8 assumption)
  const int bid = blockIdx.x;
  const int xcd = bid & 7, slot = bid >> 3;      // slot 0..63
  const int h = xcd * 2 + (slot >> 5);
  const int q0 = (slot & 31) * 128;

  const int tid = threadIdx.x;
  const int w = tid >> 6, lane = tid & 63, l31 = lane & 31, l1 = lane >> 5;
  const int g = w >> 1, wg = w & 1;              // group = KV half; wg = q-wave in group
  const int kvbase = g * (T_SEQ / 2);

  // 34 KB shared: [0,16384) shorts = K staging (2 grp x 2 buf x 2048),
  // [16384,32768) = V staging; merge Oex/mex overlay the same space afterwards.
  __shared__ __align__(16) short SM[17408];

  // Q B-fragments: subtile A = q0+wg*64+l31, B = +32; k = d = ks*16 + l1*8 + j
  short8 qfA[4], qfB[4];
  {
    const short* qp = qkv + (size_t)(q0 + wg * 64 + l31) * C3 + h * 64 + l1 * 8;
#pragma unroll
    for (int ks = 0; ks < 4; ++ks) {
      qfA[ks] = *(const short8*)(qp + ks * 16);
      qfB[ks] = *(const short8*)(qp + (size_t)32 * C3 + ks * 16);
    }
  }

  f32x16 oaA0, oaA1, oaB0, oaB1;   // O^T: col q=l31, row d=(r&3)+8*(r>>2)+4*l1 (+32 for *1)
#pragma unroll
  for (int r = 0; r < 16; ++r) { oaA0[r] = 0.f; oaA1[r] = 0.f; oaB0[r] = 0.f; oaB1[r] = 0.f; }
  float mA = -INFINITY, lA = 0.f, mB = -INFINITY, lB = 0.f;
  const float SCL = 0.125f * 1.44269504f;          // 1/sqrt(64) * log2(e)
  const float TH = 8.0f / SCL;                     // defer-max threshold (p <= 2^8)

  // --- staging pointers (wave-load i covers 8 rows; rows = wg*16 + i*8 + (lane>>3)) ---
  // K tile [kv32][d64], byte-swizzled col: csw = ((lane&7)<<3) ^ ((lane>>3)<<3) shorts
  const int csw = ((lane & 7) << 3) ^ ((lane >> 3) << 3);
  const short* kpt = qkv + 1024 + h * 64 + csw +
                     (size_t)(kvbase + wg * 16 + (lane >> 3)) * C3;
  // V tile packed rows r in [0,32): [ V^T[d=r][kv0..31] | V^T[d=r+32][kv0..31] ],
  // 8x16B units XOR-swizzled by (r&7). lane's logical unit lu = (lane&7)^(lane>>3).
  const int lu = (lane & 7) ^ (lane >> 3);
  const short* vpt = vT + (size_t)(h * 64 + wg * 16 + (lane >> 3) + (lu >> 2) * 32) * T_SEQ +
                     kvbase + (lu & 3) * 8;
  const int rswz = (l31 & 7) << 3;

  short* const Kbase = SM + g * 4096;
  short* const Vbase = SM + 8192 + g * 4096;

  auto stage = [&](int buf) {
#pragma unroll
    for (int i = 0; i < 2; ++i) {
      gld_lds16(kpt + (size_t)i * 8 * C3, Kbase + buf * 2048 + wg * 1024 + i * 512);
      gld_lds16(vpt + (size_t)i * 8 * T_SEQ, Vbase + buf * 2048 + wg * 1024 + i * 512);
    }
  };

  stage(0);
  kpt += (size_t)32 * C3;
  vpt += 32;

  const int NT = (T_SEQ / 2) / 32;   // 64 tiles per group
  for (int t = 0; t < NT; ++t) {
    const int cur = t & 1;
    __builtin_amdgcn_s_barrier();            // done reading buf cur^1
    if (t + 1 < NT) {
      stage(cur ^ 1);
      kpt += (size_t)32 * C3;
      vpt += 32;
      asm volatile("s_waitcnt vmcnt(4)" ::: "memory");   // tile-t loads landed; t+1's fly
    } else {
      asm volatile("s_waitcnt vmcnt(0)" ::: "memory");
    }
    __builtin_amdgcn_s_barrier();            // tile-t data visible

    const short* Kb = Kbase + cur * 2048;
    const short* Vb = Vbase + cur * 2048;

    // S^T = K Q^T for both q-subtiles (K frags shared)
    f32x16 sA, sB;
#pragma unroll
    for (int r = 0; r < 16; ++r) { sA[r] = 0.f; sB[r] = 0.f; }
    __builtin_amdgcn_s_setprio(1);
#pragma unroll
    for (int ks = 0; ks < 4; ++ks) {
      const int c = (ks * 16 + l1 * 8) ^ rswz;
      short8 kf = *(const short8*)&Kb[l31 * 64 + c];
      sA = __builtin_amdgcn_mfma_f32_32x32x16_bf16(kf, qfA[ks], sA, 0, 0, 0);
      sB = __builtin_amdgcn_mfma_f32_32x32x16_bf16(kf, qfB[ks], sB, 0, 0, 0);
    }
    __builtin_amdgcn_s_setprio(0);

    // lane-local maxes via max3 trees
    float tmA, tmB;
    {
      float v0 = m3(sA[0], sA[1], sA[2]);
      float v1 = m3(sA[3], sA[4], sA[5]);
      float v2 = m3(sA[6], sA[7], sA[8]);
      float v3 = m3(sA[9], sA[10], sA[11]);
      float v4 = m3(sA[12], sA[13], sA[14]);
      tmA = fmaxf(m3(v0, v1, v2), m3(v3, v4, sA[15]));
      float u0 = m3(sB[0], sB[1], sB[2]);
      float u1 = m3(sB[3], sB[4], sB[5]);
      float u2 = m3(sB[6], sB[7], sB[8]);
      float u3 = m3(sB[9], sB[10], sB[11]);
      float u4 = m3(sB[12], sB[13], sB[14]);
      tmB = fmaxf(m3(u0, u1, u2), m3(u3, u4, sB[15]));
    }

    // defer-max: single 64-lane ballot for both subtiles keeps halves consistent
    if (__any(fmaxf(tmA - mA, tmB - mB) > TH)) {
      const float txA = max_half64(tmA);
      const float mnA = fmaxf(mA, txA);
      const float alA = exp2_fast((mA - mnA) * SCL);
      mA = mnA; lA *= alA;
      const float txB = max_half64(tmB);
      const float mnB = fmaxf(mB, txB);
      const float alB = exp2_fast((mB - mnB) * SCL);
      mB = mnB; lB *= alB;
#pragma unroll
      for (int r = 0; r < 16; ++r) {
        oaA0[r] *= alA; oaA1[r] *= alA;
        oaB0[r] *= alB; oaB1[r] *= alB;
      }
    }
    const float mscA = mA * SCL, mscB = mB * SCL;
#pragma unroll
    for (int r = 0; r < 16; ++r) sA[r] = exp2_fast(fmaf(sA[r], SCL, -mscA));
#pragma unroll
    for (int r = 0; r < 16; ++r) sB[r] = exp2_fast(fmaf(sB[r], SCL, -mscB));

    // per-lane partial row-sums (cross-half combine deferred to the end)
    {
      float u[8];
#pragma unroll
      for (int r = 0; r < 8; ++r) u[r] = sA[r] + sA[r + 8];
#pragma unroll
      for (int r = 0; r < 4; ++r) u[r] += u[r + 4];
      lA += (u[0] + u[2]) + (u[1] + u[3]);
#pragma unroll
      for (int r = 0; r < 8; ++r) u[r] = sB[r] + sB[r + 8];
#pragma unroll
      for (int r = 0; r < 4; ++r) u[r] += u[r + 4];
      lB += (u[0] + u[2]) + (u[1] + u[3]);
    }

    // P -> B-fragments in-register: cvt_pk + permlane32_swap (T12)
    unsigned pwA[2][4], pwB[2][4];
#pragma unroll
    for (int kh = 0; kh < 2; ++kh) {
      {
        unsigned x0 = cvt_pk_bf16(sA[kh * 8 + 0], sA[kh * 8 + 1]);
        unsigned y0 = cvt_pk_bf16(sA[kh * 8 + 4], sA[kh * 8 + 5]);
        asm volatile("s_nop 0\n\tv_permlane32_swap_b32 %0, %1" : "+v"(x0), "+v"(y0));
        unsigned x1 = cvt_pk_bf16(sA[kh * 8 + 2], sA[kh * 8 + 3]);
        unsigned y1 = cvt_pk_bf16(sA[kh * 8 + 6], sA[kh * 8 + 7]);
        asm volatile("s_nop 0\n\tv_permlane32_swap_b32 %0, %1" : "+v"(x1), "+v"(y1));
        pwA[kh][0] = x0; pwA[kh][1] = x1; pwA[kh][2] = y0; pwA[kh][3] = y1;
      }
      {
        unsigned x0 = cvt_pk_bf16(sB[kh * 8 + 0], sB[kh * 8 + 1]);
        unsigned y0 = cvt_pk_bf16(sB[kh * 8 + 4], sB[kh * 8 + 5]);
        asm volatile("s_nop 0\n\tv_permlane32_swap_b32 %0, %1" : "+v"(x0), "+v"(y0));
        unsigned x1 = cvt_pk_bf16(sB[kh * 8 + 2], sB[kh * 8 + 3]);
        unsigned y1 = cvt_pk_bf16(sB[kh * 8 + 6], sB[kh * 8 + 7]);
        asm volatile("s_nop 0\n\tv_permlane32_swap_b32 %0, %1" : "+v"(x1), "+v"(y1));
        pwB[kh][0] = x0; pwB[kh][1] = x1; pwB[kh][2] = y0; pwB[kh][3] = y1;
      }
    }

    // O^T += V^T P^T (V frags shared across subtiles)
    __builtin_amdgcn_s_setprio(1);
#pragma unroll
    for (int kh = 0; kh < 2; ++kh) {
      union { unsigned u[4]; short8 s8; } ua, ub;
      ua.u[0] = pwA[kh][0]; ua.u[1] = pwA[kh][1]; ua.u[2] = pwA[kh][2]; ua.u[3] = pwA[kh][3];
      ub.u[0] = pwB[kh][0]; ub.u[1] = pwB[kh][1]; ub.u[2] = pwB[kh][2]; ub.u[3] = pwB[kh][3];
      {
        const int unit = ((0 * 4 + kh * 2 + l1) ^ (l31 & 7));
        short8 vf = *(const short8*)&Vb[l31 * 64 + unit * 8];
        oaA0 = __builtin_amdgcn_mfma_f32_32x32x16_bf16(vf, ua.s8, oaA0, 0, 0, 0);
        oaB0 = __builtin_amdgcn_mfma_f32_32x32x16_bf16(vf, ub.s8, oaB0, 0, 0, 0);
      }
      {
        const int unit = ((1 * 4 + kh * 2 + l1) ^ (l31 & 7));
        short8 vf = *(const short8*)&Vb[l31 * 64 + unit * 8];
        oaA1 = __builtin_amdgcn_mfma_f32_32x32x16_bf16(vf, ua.s8, oaA1, 0, 0, 0);
        oaB1 = __builtin_amdgcn_mfma_f32_32x32x16_bf16(vf, ub.s8, oaB1, 0, 0, 0);
      }
    }
    __builtin_amdgcn_s_setprio(0);
  }

  // finalize per-lane l across the two lane-halves (m already ballot-consistent)
  lA += __shfl_xor(lA, 32, 64);
  lB += __shfl_xor(lB, 32, 64);

  // ---- merge KV halves between wave pairs (w, w+2), then store ----
  __syncthreads();                          // all staging reads done; reuse SM
  float* Oex = (float*)SM;                  // [pair][r<64][lane] = 8192 floats
  float* mex = ((float*)SM) + 8192;         // [pair][lane][4]    = 512 floats
  if (g == 1) {
    float* ob = Oex + wg * 4096;
#pragma unroll
    for (int r = 0; r < 16; ++r) {
      ob[r * 64 + lane] = oaA0[r];
      ob[(16 + r) * 64 + lane] = oaA1[r];
      ob[(32 + r) * 64 + lane] = oaB0[r];
      ob[(48 + r) * 64 + lane] = oaB1[r];
    }
    float4 ml = {mA, lA, mB, lB};
    *(float4*)&mex[wg * 256 + lane * 4] = ml;
  }
  __syncthreads();
  if (g == 0) {
    const float4 ml = *(const float4*)&mex[wg * 256 + lane * 4];
    const float* ob = Oex + wg * 4096;
    // subtile A
    {
      const float mm = fmaxf(mA, ml.x);
      const float a = exp2_fast((mA - mm) * SCL);
      const float b = exp2_fast((ml.x - mm) * SCL);
      const float rl = 1.0f / (lA * a + ml.y * b);
      const float ra = a * rl, rb = b * rl;
      const size_t yb = (size_t)(q0 + wg * 64 + l31) * C_DIM + h * 64;
#pragma unroll
      for (int g4 = 0; g4 < 4; ++g4) {
        short4v o0, o1;
#pragma unroll
        for (int j = 0; j < 4; ++j) {
          o0[j] = f2bf(oaA0[g4 * 4 + j] * ra + ob[(g4 * 4 + j) * 64 + lane] * rb);
          o1[j] = f2bf(oaA1[g4 * 4 + j] * ra + ob[(16 + g4 * 4 + j) * 64 + lane] * rb);
        }
        *(short4v*)&y[yb + g4 * 8 + l1 * 4] = o0;
        *(short4v*)&y[yb + 32 + g4 * 8 + l1 * 4] = o1;
      }
    }
    // subtile B
    {
      const float mm = fmaxf(mB, ml.z);
      const float a = exp2_fast((mB - mm) * SCL);
      const float b = exp2_fast((ml.z - mm) * SCL);
      const float rl = 1.0f / (lB * a + ml.w * b);
      const float ra = a * rl, rb = b * rl;
      const size_t yb = (size_t)(q0 + wg * 64 + 32 + l31) * C_DIM + h * 64;
#pragma unroll
      for (int g4 = 0; g4 < 4; ++g4) {
        short4v o0, o1;
#pragma unroll
        for (int j = 0; j < 4; ++j) {
          o0[j] = f2bf(oaB0[g4 * 4 + j] * ra + ob[(32 + g4 * 4 + j) * 64 + lane] * rb);
          o1[j] = f2bf(oaB1[g4 * 4 + j] * ra + ob[(48 + g4 * 4 + j) * 64 + lane] * rb);
        }
        *(short4v*)&y[yb + g4 * 8 + l1 * 4] = o0;
        *(short4v*)&y[yb + 32 + g4 * 8 + l1 * 4] = o1;
      }
    }
  }
}

extern "C" void kernel_launch(void* const* d_in, const int* in_sizes, int n_in,
                              void* d_out, int out_size, void* d_ws, size_t ws_size,
                              hipStream_t stream) {
  const float* x = (const float*)d_in[0];       // [T, C]
  const float* w_qkv = (const float*)d_in[1];   // [C, 3C]
  const float* w_out = (const float*)d_in[2];   // [C, C]
  float* out = (float*)d_out;                   // [T, C] fp32

  char* ws = (char*)d_ws;
  short* xb = (short*)ws;            ws += (size_t)T_SEQ * C_DIM * 2;       // 8 MB
  short* wqT = (short*)ws;           ws += (size_t)C3 * C_DIM * 2;          // 6 MB
  short* woT = (short*)ws;           ws += (size_t)C_DIM * C_DIM * 2;       // 2 MB
  short* qkv = (short*)ws;           ws += (size_t)T_SEQ * C3 * 2;          // 24 MB
  short* vT = (short*)ws;            ws += (size_t)NH * T_SEQ * HD * 2;     // 8 MB
  short* y = (short*)ws;             ws += (size_t)T_SEQ * C_DIM * 2;       // 8 MB

  // 1. convert inputs to bf16 (weights transposed to [N][K]; one fused launch)
  conv_bf16_kernel<<<(T_SEQ * C_DIM) / (256 * 8), 256, 0, stream>>>(x, xb);
  trans_conv2_kernel<<<dim3(C3 / 32 + C_DIM / 32, C_DIM / 32), dim3(32, 8), 0, stream>>>(
      w_qkv, wqT, w_out, woT);

  // 2. qkv = x @ w_qkv (bf16 out); V-columns (>=2048) written transposed into vT
  gemm_bt_kernel<<<dim3(C3 / 128, T_SEQ / 128), 256, 0, stream>>>(xb, wqT, qkv, vT, 2048,
                                                                  T_SEQ, C3, C_DIM);

  // 3. flash attention -> y [T, C] bf16
  attn_kernel<<<512, 256, 0, stream>>>(qkv, vT, y);

  // 4. out = y @ w_out (fp32 out), 128x64 tiles -> 512 blocks = 2/CU
  gemm_bt64_kernel<<<dim3(C_DIM / 64, T_SEQ / 128), 256, 0, stream>>>(y, woT, out,
                                                                      T_SEQ, C_DIM, C_DIM);
}

// Round 19
// 161.993 us; speedup vs baseline: 1.8810x; 1.0157x over previous
//
#include <hip/hip_runtime.h>
#include <hip/hip_bf16.h>

// Sizes for this problem
#define T_SEQ 4096
#define C_DIM 1024
#define NH    16
#define HD    64
#define C3    3072

typedef __attribute__((ext_vector_type(8))) short short8;
typedef __attribute__((ext_vector_type(4))) short short4v;
typedef __attribute__((ext_vector_type(4))) float f32x4;
typedef __attribute__((ext_vector_type(16))) float f32x16;

__device__ __forceinline__ short f2bf(float f) {
  union { float f; unsigned u; } v; v.f = f;
  unsigned r = v.u + 0x7FFFu + ((v.u >> 16) & 1u);   // round-to-nearest-even
  return (short)(r >> 16);
}

__device__ __forceinline__ unsigned cvt_pk_bf16(float lo, float hi) {
  unsigned r;
  asm volatile("v_cvt_pk_bf16_f32 %0, %1, %2" : "=v"(r) : "v"(lo), "v"(hi));
  return r;
}

// single-instruction 2^x (exp2f w/o fast-math is a multi-inst ocml call)
__device__ __forceinline__ float exp2_fast(float x) {
  return __builtin_amdgcn_exp2f(x);
}

// cross-half (lane^32) max via ds_bpermute-based shfl (proven correct here;
// permlane32_swap-based reduce failed twice — suspected wait-state hazard).
__device__ __forceinline__ float max_half64(float v) {
  return fmaxf(v, __shfl_xor(v, 32, 64));
}

__device__ __forceinline__ float m3(float a, float b, float c) {
  return fmaxf(fmaxf(a, b), c);   // clang fuses to v_max3_f32
}

__device__ __forceinline__ void gld_lds16(const void* g, void* l) {
  __builtin_amdgcn_global_load_lds(
      (const __attribute__((address_space(1))) unsigned int*)g,
      (__attribute__((address_space(3))) unsigned int*)l, 16, 0, 0);
}

// ---------------- fused prep: x fp32->bf16 + both weight transpose-converts ----------------
// 256 threads as dim3(32,8). Blocks [0,2048): convert x (8 floats/thread).
// Blocks [2048,6144): 32x32 transpose-convert tiles of w_qkv (first 96*32) / w_out.
__global__ void prep_kernel(const float* __restrict__ x, short* __restrict__ xb,
                            const float* __restrict__ wq, short* __restrict__ wqT,
                            const float* __restrict__ wo, short* __restrict__ woT) {
  const int b = blockIdx.x;
  if (b < 2048) {
    const int tid = threadIdx.y * 32 + threadIdx.x;
    const size_t i = ((size_t)b * 256 + tid) * 8;
    float4 v0 = *(const float4*)(x + i);
    float4 v1 = *(const float4*)(x + i + 4);
    short8 o;
    o[0] = f2bf(v0.x); o[1] = f2bf(v0.y); o[2] = f2bf(v0.z); o[3] = f2bf(v0.w);
    o[4] = f2bf(v1.x); o[5] = f2bf(v1.y); o[6] = f2bf(v1.z); o[7] = f2bf(v1.w);
    *(short8*)(xb + i) = o;
    return;
  }
  const int b2 = b - 2048;                    // 0..4095
  int bx = b2 & 127, by = b2 >> 7;            // 128 col-tiles x 32 k-tiles
  const float* in;
  short* out;
  int N;
  if (bx < C3 / 32) { in = wq; out = wqT; N = C3; }
  else              { in = wo; out = woT; N = C_DIM; bx -= C3 / 32; }
  const int K = C_DIM;
  __shared__ float t[32][33];
  const int n0 = bx * 32, k0 = by * 32;
  const int tx = threadIdx.x, ty = threadIdx.y;
  for (int i = ty; i < 32; i += 8) t[i][tx] = in[(size_t)(k0 + i) * N + n0 + tx];
  __syncthreads();
  for (int i = ty; i < 32; i += 8) out[(size_t)(n0 + i) * K + k0 + tx] = f2bf(t[tx][i]);
}

// ---------------- bf16 GEMM: C[M,N] = A[M,K] * BT[N,K]^T (128x128 tile) ----------------
// Blocks with bn >= vcol0 write their tile TRANSPOSED into vTout[(col-vcol0)*M + row]
// (bf16), fusing the V-repack into the epilogue; other blocks write C normally.
__global__ __launch_bounds__(256) void gemm_bt_kernel(const short* __restrict__ A,
                                                      const short* __restrict__ BT,
                                                      short* __restrict__ C,
                                                      short* __restrict__ vTout,
                                                      int vcol0,
                                                      int M, int N, int K) {
  __shared__ __align__(16) short As[128 * 32];
  __shared__ __align__(16) short Bs[128 * 32];
  const int tid = threadIdx.x;
  const int wid = tid >> 6;
  const int lane = tid & 63;
  const int l15 = lane & 15;
  const int l4 = lane >> 4;
  const int wr = wid >> 1;
  const int wc = wid & 1;

  // XCD-aware bijective swizzle (grid count divisible by 8)
  const int nwg = gridDim.x * gridDim.y;
  int lin = blockIdx.y * gridDim.x + blockIdx.x;
  lin = (lin & 7) * (nwg >> 3) + (lin >> 3);
  const int bm = (lin / gridDim.x) * 128;
  const int bn = (lin % gridDim.x) * 128;

  f32x4 acc[4][4];
#pragma unroll
  for (int m = 0; m < 4; ++m)
#pragma unroll
    for (int n = 0; n < 4; ++n) acc[m][n] = (f32x4){0.f, 0.f, 0.f, 0.f};

  const int ebase = wid * 1024;              // 1024 bf16 elements per wave (2 x 512)
  const int e0 = ebase + lane * 8;
  const int r0 = e0 >> 5, c0 = e0 & 31;
  const int r1 = r0 + 16;                    // e0 + 512

  for (int k0 = 0; k0 < K; k0 += 32) {
    __syncthreads();
    gld_lds16(A + (size_t)(bm + r0) * K + k0 + c0, As + ebase);
    gld_lds16(A + (size_t)(bm + r1) * K + k0 + c0, As + ebase + 512);
    gld_lds16(BT + (size_t)(bn + r0) * K + k0 + c0, Bs + ebase);
    gld_lds16(BT + (size_t)(bn + r1) * K + k0 + c0, Bs + ebase + 512);
    __syncthreads();

    short8 a[4], b[4];
#pragma unroll
    for (int m = 0; m < 4; ++m)
      a[m] = *(const short8*)&As[(wr * 64 + m * 16 + l15) * 32 + l4 * 8];
#pragma unroll
    for (int n = 0; n < 4; ++n)
      b[n] = *(const short8*)&Bs[(wc * 64 + n * 16 + l15) * 32 + l4 * 8];
#pragma unroll
    for (int m = 0; m < 4; ++m)
#pragma unroll
      for (int n = 0; n < 4; ++n)
        acc[m][n] = __builtin_amdgcn_mfma_f32_16x16x32_bf16(a[m], b[n], acc[m][n], 0, 0, 0);
  }

  if (bn >= vcol0) {
    // V-part block: vTout[(col - vcol0)][row] ; 4 consecutive rows -> one short4 store
#pragma unroll
    for (int m = 0; m < 4; ++m) {
      const int row0 = bm + wr * 64 + m * 16 + l4 * 4;
#pragma unroll
      for (int n = 0; n < 4; ++n) {
        const int col = bn + wc * 64 + n * 16 + l15;
        short4v o;
#pragma unroll
        for (int r = 0; r < 4; ++r) o[r] = f2bf(acc[m][n][r]);
        *(short4v*)&vTout[(size_t)(col - vcol0) * M + row0] = o;
      }
    }
  } else {
#pragma unroll
    for (int m = 0; m < 4; ++m) {
      const int row0 = bm + wr * 64 + m * 16 + l4 * 4;
#pragma unroll
      for (int n = 0; n < 4; ++n) {
        const int col = bn + wc * 64 + n * 16 + l15;
#pragma unroll
        for (int r = 0; r < 4; ++r)
          C[(size_t)(row0 + r) * N + col] = f2bf(acc[m][n][r]);
      }
    }
  }
}

// ---------------- bf16 GEMM: 128x64 tile, fp32 out (GEMM2: 2 blocks/CU) ----------------
__global__ __launch_bounds__(256) void gemm_bt64_kernel(const short* __restrict__ A,
                                                        const short* __restrict__ BT,
                                                        float* __restrict__ C,
                                                        int M, int N, int K) {
  __shared__ __align__(16) short As[128 * 32];
  __shared__ __align__(16) short Bs[64 * 32];
  const int tid = threadIdx.x;
  const int wid = tid >> 6;
  const int lane = tid & 63;
  const int l15 = lane & 15;
  const int l4 = lane >> 4;
  const int wr = wid >> 1;                   // 0..1 -> 64-row half
  const int wc = wid & 1;                    // 0..1 -> 32-col half

  const int nwg = gridDim.x * gridDim.y;
  int lin = blockIdx.y * gridDim.x + blockIdx.x;
  lin = (lin & 7) * (nwg >> 3) + (lin >> 3);
  const int bm = (lin / gridDim.x) * 128;
  const int bn = (lin % gridDim.x) * 64;

  f32x4 acc[4][2];
#pragma unroll
  for (int m = 0; m < 4; ++m)
#pragma unroll
    for (int n = 0; n < 2; ++n) acc[m][n] = (f32x4){0.f, 0.f, 0.f, 0.f};

  const int ebase = wid * 1024;
  const int e0 = ebase + lane * 8;
  const int r0 = e0 >> 5, c0 = e0 & 31;
  const int r1 = r0 + 16;
  const int eb = wid * 512 + lane * 8;       // B: 64x32 = 2048 elems, 512/wave
  const int rb = eb >> 5, cb = eb & 31;

  for (int k0 = 0; k0 < K; k0 += 32) {
    __syncthreads();
    gld_lds16(A + (size_t)(bm + r0) * K + k0 + c0, As + ebase);
    gld_lds16(A + (size_t)(bm + r1) * K + k0 + c0, As + ebase + 512);
    gld_lds16(BT + (size_t)(bn + rb) * K + k0 + cb, Bs + eb);
    __syncthreads();

    short8 a[4], b[2];
#pragma unroll
    for (int m = 0; m < 4; ++m)
      a[m] = *(const short8*)&As[(wr * 64 + m * 16 + l15) * 32 + l4 * 8];
#pragma unroll
    for (int n = 0; n < 2; ++n)
      b[n] = *(const short8*)&Bs[(wc * 32 + n * 16 + l15) * 32 + l4 * 8];
#pragma unroll
    for (int m = 0; m < 4; ++m)
#pragma unroll
      for (int n = 0; n < 2; ++n)
        acc[m][n] = __builtin_amdgcn_mfma_f32_16x16x32_bf16(a[m], b[n], acc[m][n], 0, 0, 0);
  }

#pragma unroll
  for (int m = 0; m < 4; ++m) {
    const int row0 = bm + wr * 64 + m * 16 + l4 * 4;
#pragma unroll
    for (int n = 0; n < 2; ++n) {
      const int col = bn + wc * 32 + n * 16 + l15;
#pragma unroll
      for (int r = 0; r < 4; ++r)
        C[(size_t)(row0 + r) * N + col] = acc[m][n][r];
    }
  }
}

// ---------------- flash attention: 64 q per wave (2 subtiles share K/V frags) ----------------
// 512 blocks x 256 threads = 4 waves: waves {0,1} q rows [q0+w*64,+64) on KV half 0;
// waves {2,3} same q on KV half 1. KVBLK=32, counted-vmcnt double-buffer, end merge via LDS.
__global__ __launch_bounds__(256, 2) void attn_kernel(const short* __restrict__ qkv,
                                                      const short* __restrict__ vT,
                                                      short* __restrict__ y) {
  // XCD-aware: heads {2x, 2x+1} -> XCD x (round-robin bid%8 assumption)
  const int bid = blockIdx.x;
  const int xcd = bid & 7, slot = bid >> 3;      // slot 0..63
  const int h = xcd * 2 + (slot >> 5);
  const int q0 = (slot & 31) * 128;

  const int tid = threadIdx.x;
  const int w = tid >> 6, lane = tid & 63, l31 = lane & 31, l1 = lane >> 5;
  const int g = w >> 1, wg = w & 1;              // group = KV half; wg = q-wave in group
  const int kvbase = g * (T_SEQ / 2);

  // 34 KB shared: [0,16384) shorts = K staging (2 grp x 2 buf x 2048),
  // [16384,32768) = V staging; merge Oex/mex overlay the same space afterwards.
  __shared__ __align__(16) short SM[17408];

  // Q B-fragments: subtile A = q0+wg*64+l31, B = +32; k = d = ks*16 + l1*8 + j
  short8 qfA[4], qfB[4];
  {
    const short* qp = qkv + (size_t)(q0 + wg * 64 + l31) * C3 + h * 64 + l1 * 8;
#pragma unroll
    for (int ks = 0; ks < 4; ++ks) {
      qfA[ks] = *(const short8*)(qp + ks * 16);
      qfB[ks] = *(const short8*)(qp + (size_t)32 * C3 + ks * 16);
    }
  }

  f32x16 oaA0, oaA1, oaB0, oaB1;   // O^T: col q=l31, row d=(r&3)+8*(r>>2)+4*l1 (+32 for *1)
#pragma unroll
  for (int r = 0; r < 16; ++r) { oaA0[r] = 0.f; oaA1[r] = 0.f; oaB0[r] = 0.f; oaB1[r] = 0.f; }
  float mA = -INFINITY, lA = 0.f, mB = -INFINITY, lB = 0.f;
  const float SCL = 0.125f * 1.44269504f;          // 1/sqrt(64) * log2(e)
  const float TH = 8.0f / SCL;                     // defer-max threshold (p <= 2^8)

  // --- staging pointers (wave-load i covers 8 rows; rows = wg*16 + i*8 + (lane>>3)) ---
  // K tile [kv32][d64], byte-swizzled col: csw = ((lane&7)<<3) ^ ((lane>>3)<<3) shorts
  const int csw = ((lane & 7) << 3) ^ ((lane >> 3) << 3);
  const short* kpt = qkv + 1024 + h * 64 + csw +
                     (size_t)(kvbase + wg * 16 + (lane >> 3)) * C3;
  // V tile packed rows r in [0,32): [ V^T[d=r][kv0..31] | V^T[d=r+32][kv0..31] ],
  // 8x16B units XOR-swizzled by (r&7). lane's logical unit lu = (lane&7)^(lane>>3).
  const int lu = (lane & 7) ^ (lane >> 3);
  const short* vpt = vT + (size_t)(h * 64 + wg * 16 + (lane >> 3) + (lu >> 2) * 32) * T_SEQ +
                     kvbase + (lu & 3) * 8;
  const int rswz = (l31 & 7) << 3;

  short* const Kbase = SM + g * 4096;
  short* const Vbase = SM + 8192 + g * 4096;

  auto stage = [&](int buf) {
#pragma unroll
    for (int i = 0; i < 2; ++i) {
      gld_lds16(kpt + (size_t)i * 8 * C3, Kbase + buf * 2048 + wg * 1024 + i * 512);
      gld_lds16(vpt + (size_t)i * 8 * T_SEQ, Vbase + buf * 2048 + wg * 1024 + i * 512);
    }
  };

  stage(0);
  kpt += (size_t)32 * C3;
  vpt += 32;

  const int NT = (T_SEQ / 2) / 32;   // 64 tiles per group
  for (int t = 0; t < NT; ++t) {
    const int cur = t & 1;
    __builtin_amdgcn_s_barrier();            // done reading buf cur^1
    if (t + 1 < NT) {
      stage(cur ^ 1);
      kpt += (size_t)32 * C3;
      vpt += 32;
      asm volatile("s_waitcnt vmcnt(4)" ::: "memory");   // tile-t loads landed; t+1's fly
    } else {
      asm volatile("s_waitcnt vmcnt(0)" ::: "memory");
    }
    __builtin_amdgcn_s_barrier();            // tile-t data visible

    const short* Kb = Kbase + cur * 2048;
    const short* Vb = Vbase + cur * 2048;

    // S^T = K Q^T for both q-subtiles (K frags shared)
    f32x16 sA, sB;
#pragma unroll
    for (int r = 0; r < 16; ++r) { sA[r] = 0.f; sB[r] = 0.f; }
    __builtin_amdgcn_s_setprio(1);
#pragma unroll
    for (int ks = 0; ks < 4; ++ks) {
      const int c = (ks * 16 + l1 * 8) ^ rswz;
      short8 kf = *(const short8*)&Kb[l31 * 64 + c];
      sA = __builtin_amdgcn_mfma_f32_32x32x16_bf16(kf, qfA[ks], sA, 0, 0, 0);
      sB = __builtin_amdgcn_mfma_f32_32x32x16_bf16(kf, qfB[ks], sB, 0, 0, 0);
    }
    __builtin_amdgcn_s_setprio(0);

    // lane-local maxes via max3 trees
    float tmA, tmB;
    {
      float v0 = m3(sA[0], sA[1], sA[2]);
      float v1 = m3(sA[3], sA[4], sA[5]);
      float v2 = m3(sA[6], sA[7], sA[8]);
      float v3 = m3(sA[9], sA[10], sA[11]);
      float v4 = m3(sA[12], sA[13], sA[14]);
      tmA = fmaxf(m3(v0, v1, v2), m3(v3, v4, sA[15]));
      float u0 = m3(sB[0], sB[1], sB[2]);
      float u1 = m3(sB[3], sB[4], sB[5]);
      float u2 = m3(sB[6], sB[7], sB[8]);
      float u3 = m3(sB[9], sB[10], sB[11]);
      float u4 = m3(sB[12], sB[13], sB[14]);
      tmB = fmaxf(m3(u0, u1, u2), m3(u3, u4, sB[15]));
    }

    // defer-max: single 64-lane ballot for both subtiles keeps halves consistent
    if (__any(fmaxf(tmA - mA, tmB - mB) > TH)) {
      const float txA = max_half64(tmA);
      const float mnA = fmaxf(mA, txA);
      const float alA = exp2_fast((mA - mnA) * SCL);
      mA = mnA; lA *= alA;
      const float txB = max_half64(tmB);
      const float mnB = fmaxf(mB, txB);
      const float alB = exp2_fast((mB - mnB) * SCL);
      mB = mnB; lB *= alB;
#pragma unroll
      for (int r = 0; r < 16; ++r) {
        oaA0[r] *= alA; oaA1[r] *= alA;
        oaB0[r] *= alB; oaB1[r] *= alB;
      }
    }
    const float mscA = mA * SCL, mscB = mB * SCL;
#pragma unroll
    for (int r = 0; r < 16; ++r) sA[r] = exp2_fast(fmaf(sA[r], SCL, -mscA));
#pragma unroll
    for (int r = 0; r < 16; ++r) sB[r] = exp2_fast(fmaf(sB[r], SCL, -mscB));

    // per-lane partial row-sums (cross-half combine deferred to the end)
    {
      float u[8];
#pragma unroll
      for (int r = 0; r < 8; ++r) u[r] = sA[r] + sA[r + 8];
#pragma unroll
      for (int r = 0; r < 4; ++r) u[r] += u[r + 4];
      lA += (u[0] + u[2]) + (u[1] + u[3]);
#pragma unroll
      for (int r = 0; r < 8; ++r) u[r] = sB[r] + sB[r + 8];
#pragma unroll
      for (int r = 0; r < 4; ++r) u[r] += u[r + 4];
      lB += (u[0] + u[2]) + (u[1] + u[3]);
    }

    // P -> B-fragments in-register: cvt_pk + permlane32_swap (T12)
    unsigned pwA[2][4], pwB[2][4];
#pragma unroll
    for (int kh = 0; kh < 2; ++kh) {
      {
        unsigned x0 = cvt_pk_bf16(sA[kh * 8 + 0], sA[kh * 8 + 1]);
        unsigned y0 = cvt_pk_bf16(sA[kh * 8 + 4], sA[kh * 8 + 5]);
        asm volatile("s_nop 0\n\tv_permlane32_swap_b32 %0, %1" : "+v"(x0), "+v"(y0));
        unsigned x1 = cvt_pk_bf16(sA[kh * 8 + 2], sA[kh * 8 + 3]);
        unsigned y1 = cvt_pk_bf16(sA[kh * 8 + 6], sA[kh * 8 + 7]);
        asm volatile("s_nop 0\n\tv_permlane32_swap_b32 %0, %1" : "+v"(x1), "+v"(y1));
        pwA[kh][0] = x0; pwA[kh][1] = x1; pwA[kh][2] = y0; pwA[kh][3] = y1;
      }
      {
        unsigned x0 = cvt_pk_bf16(sB[kh * 8 + 0], sB[kh * 8 + 1]);
        unsigned y0 = cvt_pk_bf16(sB[kh * 8 + 4], sB[kh * 8 + 5]);
        asm volatile("s_nop 0\n\tv_permlane32_swap_b32 %0, %1" : "+v"(x0), "+v"(y0));
        unsigned x1 = cvt_pk_bf16(sB[kh * 8 + 2], sB[kh * 8 + 3]);
        unsigned y1 = cvt_pk_bf16(sB[kh * 8 + 6], sB[kh * 8 + 7]);
        asm volatile("s_nop 0\n\tv_permlane32_swap_b32 %0, %1" : "+v"(x1), "+v"(y1));
        pwB[kh][0] = x0; pwB[kh][1] = x1; pwB[kh][2] = y0; pwB[kh][3] = y1;
      }
    }

    // O^T += V^T P^T (V frags shared across subtiles)
    __builtin_amdgcn_s_setprio(1);
#pragma unroll
    for (int kh = 0; kh < 2; ++kh) {
      union { unsigned u[4]; short8 s8; } ua, ub;
      ua.u[0] = pwA[kh][0]; ua.u[1] = pwA[kh][1]; ua.u[2] = pwA[kh][2]; ua.u[3] = pwA[kh][3];
      ub.u[0] = pwB[kh][0]; ub.u[1] = pwB[kh][1]; ub.u[2] = pwB[kh][2]; ub.u[3] = pwB[kh][3];
      {
        const int unit = ((0 * 4 + kh * 2 + l1) ^ (l31 & 7));
        short8 vf = *(const short8*)&Vb[l31 * 64 + unit * 8];
        oaA0 = __builtin_amdgcn_mfma_f32_32x32x16_bf16(vf, ua.s8, oaA0, 0, 0, 0);
        oaB0 = __builtin_amdgcn_mfma_f32_32x32x16_bf16(vf, ub.s8, oaB0, 0, 0, 0);
      }
      {
        const int unit = ((1 * 4 + kh * 2 + l1) ^ (l31 & 7));
        short8 vf = *(const short8*)&Vb[l31 * 64 + unit * 8];
        oaA1 = __builtin_amdgcn_mfma_f32_32x32x16_bf16(vf, ua.s8, oaA1, 0, 0, 0);
        oaB1 = __builtin_amdgcn_mfma_f32_32x32x16_bf16(vf, ub.s8, oaB1, 0, 0, 0);
      }
    }
    __builtin_amdgcn_s_setprio(0);
  }

  // finalize per-lane l across the two lane-halves (m already ballot-consistent)
  lA += __shfl_xor(lA, 32, 64);
  lB += __shfl_xor(lB, 32, 64);

  // ---- merge KV halves between wave pairs (w, w+2), then store ----
  __syncthreads();                          // all staging reads done; reuse SM
  float* Oex = (float*)SM;                  // [pair][r<64][lane] = 8192 floats
  float* mex = ((float*)SM) + 8192;         // [pair][lane][4]    = 512 floats
  if (g == 1) {
    float* ob = Oex + wg * 4096;
#pragma unroll
    for (int r = 0; r < 16; ++r) {
      ob[r * 64 + lane] = oaA0[r];
      ob[(16 + r) * 64 + lane] = oaA1[r];
      ob[(32 + r) * 64 + lane] = oaB0[r];
      ob[(48 + r) * 64 + lane] = oaB1[r];
    }
    float4 ml = {mA, lA, mB, lB};
    *(float4*)&mex[wg * 256 + lane * 4] = ml;
  }
  __syncthreads();
  if (g == 0) {
    const float4 ml = *(const float4*)&mex[wg * 256 + lane * 4];
    const float* ob = Oex + wg * 4096;
    // subtile A
    {
      const float mm = fmaxf(mA, ml.x);
      const float a = exp2_fast((mA - mm) * SCL);
      const float b = exp2_fast((ml.x - mm) * SCL);
      const float rl = 1.0f / (lA * a + ml.y * b);
      const float ra = a * rl, rb = b * rl;
      const size_t yb = (size_t)(q0 + wg * 64 + l31) * C_DIM + h * 64;
#pragma unroll
      for (int g4 = 0; g4 < 4; ++g4) {
        short4v o0, o1;
#pragma unroll
        for (int j = 0; j < 4; ++j) {
          o0[j] = f2bf(oaA0[g4 * 4 + j] * ra + ob[(g4 * 4 + j) * 64 + lane] * rb);
          o1[j] = f2bf(oaA1[g4 * 4 + j] * ra + ob[(16 + g4 * 4 + j) * 64 + lane] * rb);
        }
        *(short4v*)&y[yb + g4 * 8 + l1 * 4] = o0;
        *(short4v*)&y[yb + 32 + g4 * 8 + l1 * 4] = o1;
      }
    }
    // subtile B
    {
      const float mm = fmaxf(mB, ml.z);
      const float a = exp2_fast((mB - mm) * SCL);
      const float b = exp2_fast((ml.z - mm) * SCL);
      const float rl = 1.0f / (lB * a + ml.w * b);
      const float ra = a * rl, rb = b * rl;
      const size_t yb = (size_t)(q0 + wg * 64 + 32 + l31) * C_DIM + h * 64;
#pragma unroll
      for (int g4 = 0; g4 < 4; ++g4) {
        short4v o0, o1;
#pragma unroll
        for (int j = 0; j < 4; ++j) {
          o0[j] = f2bf(oaB0[g4 * 4 + j] * ra + ob[(32 + g4 * 4 + j) * 64 + lane] * rb);
          o1[j] = f2bf(oaB1[g4 * 4 + j] * ra + ob[(48 + g4 * 4 + j) * 64 + lane] * rb);
        }
        *(short4v*)&y[yb + g4 * 8 + l1 * 4] = o0;
        *(short4v*)&y[yb + 32 + g4 * 8 + l1 * 4] = o1;
      }
    }
  }
}

extern "C" void kernel_launch(void* const* d_in, const int* in_sizes, int n_in,
                              void* d_out, int out_size, void* d_ws, size_t ws_size,
                              hipStream_t stream) {
  const float* x = (const float*)d_in[0];       // [T, C]
  const float* w_qkv = (const float*)d_in[1];   // [C, 3C]
  const float* w_out = (const float*)d_in[2];   // [C, C]
  float* out = (float*)d_out;                   // [T, C] fp32

  char* ws = (char*)d_ws;
  short* xb = (short*)ws;            ws += (size_t)T_SEQ * C_DIM * 2;       // 8 MB
  short* wqT = (short*)ws;           ws += (size_t)C3 * C_DIM * 2;          // 6 MB
  short* woT = (short*)ws;           ws += (size_t)C_DIM * C_DIM * 2;       // 2 MB
  short* qkv = (short*)ws;           ws += (size_t)T_SEQ * C3 * 2;          // 24 MB
  short* vT = (short*)ws;            ws += (size_t)NH * T_SEQ * HD * 2;     // 8 MB
  short* y = (short*)ws;             ws += (size_t)T_SEQ * C_DIM * 2;       // 8 MB

  // 1. fused prep: x -> bf16; weights -> transposed bf16 (one launch)
  prep_kernel<<<2048 + 4096, dim3(32, 8), 0, stream>>>(x, xb, w_qkv, wqT, w_out, woT);

  // 2. qkv = x @ w_qkv (bf16 out); V-columns (>=2048) written transposed into vT
  gemm_bt_kernel<<<dim3(C3 / 128, T_SEQ / 128), 256, 0, stream>>>(xb, wqT, qkv, vT, 2048,
                                                                  T_SEQ, C3, C_DIM);

  // 3. flash attention -> y [T, C] bf16
  attn_kernel<<<512, 256, 0, stream>>>(qkv, vT, y);

  // 4. out = y @ w_out (fp32 out), 128x64 tiles -> 512 blocks = 2/CU
  gemm_bt64_kernel<<<dim3(C_DIM / 64, T_SEQ / 128), 256, 0, stream>>>(y, woT, out,
                                                                      T_SEQ, C_DIM, C_DIM);
}